// Round 7
// baseline (3912.636 us; speedup 1.0000x reference)
//
#include <hip/hip_runtime.h>
#include <math.h>

#define NB 8
#define NMEM 196608
#define NOP 65536
#define NBLK_MEM 768
#define LSEG 512
#define EPB 4096
#define NC_MEM 48   // NMEM / EPB
#define NC_OP 16    // NOP / EPB
#define NBLK2 192   // conv2 blocks per batch (128 rows each)

static __device__ __forceinline__ unsigned keymap(float f) {
  unsigned u = __float_as_uint(f);
  return (u & 0x80000000u) ? ~u : (u | 0x80000000u);
}

// logsumexp state combiner: (M,T) represents M + log(T); T==0 is identity.
static __device__ __forceinline__ void comb(float& M1, float& T1, float M2, float T2) {
  if (T2 == 0.f) return;
  if (T1 == 0.f) { M1 = M2; T1 = T2; return; }
  float M = fmaxf(M1, M2);
  T1 = T1 * expf(M1 - M) + T2 * expf(M2 - M);
  M1 = M;
}

__global__ void k_zero(double* acc) {
  if (threadIdx.x < 32) acc[threadIdx.x] = 0.0;
}

// ---- radix sort: 4x8-bit passes, stable, 4096 elements/block ----
// pass 0 variants build keys on the fly from ml+gm (bit-exact same fp add).
__global__ void k_radix_hist0(const float* __restrict__ ml, const float* __restrict__ gm,
                              unsigned* __restrict__ hist) {
  __shared__ unsigned h[256];
  int batch = blockIdx.x / NC_MEM, cb = blockIdx.x % NC_MEM;
  int t = threadIdx.x;
  h[t] = 0;
  __syncthreads();
  const float* pm = ml + (size_t)batch * NMEM + (size_t)cb * EPB;
  const float* pg = gm + (size_t)batch * NMEM + (size_t)cb * EPB;
  #pragma unroll
  for (int r = 0; r < 16; r++) {
    unsigned key = keymap(pm[r * 256 + t] + pg[r * 256 + t]);
    atomicAdd(&h[key & 255u], 1u);
  }
  __syncthreads();
  hist[((size_t)batch * 256 + t) * NC_MEM + cb] = h[t];
}

__global__ void k_radix_hist(const unsigned long long* __restrict__ src, unsigned* __restrict__ hist,
                             int nper, int nblk, int shift) {
  __shared__ unsigned h[256];
  int batch = blockIdx.x / nblk, cb = blockIdx.x % nblk;
  int t = threadIdx.x;
  h[t] = 0;
  __syncthreads();
  const unsigned long long* p = src + (size_t)batch * nper + (size_t)cb * EPB;
  #pragma unroll
  for (int r = 0; r < 16; r++) {
    unsigned long long v = p[r * 256 + t];
    unsigned d = (unsigned)(v >> shift) & 255u;
    atomicAdd(&h[d], 1u);
  }
  __syncthreads();
  hist[((size_t)batch * 256 + t) * nblk + cb] = h[t];
}

__global__ void __launch_bounds__(1024) k_radix_scan(unsigned* __restrict__ hist, int L) {
  int b = blockIdx.x, t = threadIdx.x;
  unsigned* h = hist + (size_t)b * L;
  int C = L / 1024;
  unsigned s = 0;
  for (int i = 0; i < C; i++) s += h[t * C + i];
  __shared__ unsigned ls[1024];
  ls[t] = s;
  __syncthreads();
  for (int off = 1; off < 1024; off <<= 1) {
    unsigned add = (t >= off) ? ls[t - off] : 0u;
    __syncthreads();
    ls[t] += add;
    __syncthreads();
  }
  unsigned run = (t > 0) ? ls[t - 1] : 0u;
  for (int i = 0; i < C; i++) { unsigned v = h[t * C + i]; h[t * C + i] = run; run += v; }
}

// stable in-block rank: pos = base[d] + run[d] + wave-exclusive + ballot lane rank.
#define SCATTER_BODY(GETV, WRITE)                                              \
  __shared__ unsigned base[256];                                               \
  __shared__ unsigned run[256];                                                \
  __shared__ unsigned wh[4][256];                                              \
  int t = threadIdx.x, lane = t & 63, wv = t >> 6;                             \
  base[t] = hist[((size_t)batch * 256 + t) * nblk + cb];                       \
  run[t] = 0;                                                                  \
  unsigned long long v[16];                                                    \
  GETV;                                                                        \
  __syncthreads();                                                             \
  _Pragma("unroll")                                                            \
  for (int r = 0; r < 16; r++) {                                               \
    unsigned d = (unsigned)(v[r] >> shift) & 255u;                             \
    unsigned long long m = ~0ull;                                              \
    _Pragma("unroll")                                                          \
    for (int bit = 0; bit < 8; bit++) {                                        \
      unsigned long long bal = __ballot((d >> bit) & 1u);                      \
      m &= ((d >> bit) & 1u) ? bal : ~bal;                                     \
    }                                                                          \
    unsigned rank = (unsigned)__popcll(m & ((1ull << lane) - 1ull));           \
    _Pragma("unroll")                                                          \
    for (int w = 0; w < 4; w++) wh[w][t] = 0;                                  \
    __syncthreads();                                                           \
    if (rank == 0) wh[wv][d] = (unsigned)__popcll(m);                          \
    __syncthreads();                                                           \
    {                                                                          \
      unsigned run_t = run[t];                                                 \
      _Pragma("unroll")                                                        \
      for (int w = 0; w < 4; w++) { unsigned x = wh[w][t]; wh[w][t] = run_t; run_t += x; } \
      run[t] = run_t;                                                          \
    }                                                                          \
    __syncthreads();                                                           \
    unsigned pos = base[d] + wh[wv][d] + rank;                                 \
    WRITE;                                                                     \
    __syncthreads();                                                           \
  }

__global__ void k_radix_scatter0(const float* __restrict__ ml, const float* __restrict__ gm,
                                 unsigned long long* __restrict__ dst, const unsigned* __restrict__ hist) {
  int batch = blockIdx.x / NC_MEM, cb = blockIdx.x % NC_MEM;
  const int nblk = NC_MEM, shift = 32;
  const float* pm = ml + (size_t)batch * NMEM + (size_t)cb * EPB;
  const float* pg = gm + (size_t)batch * NMEM + (size_t)cb * EPB;
  unsigned long long* q = dst + (size_t)batch * NMEM;
  SCATTER_BODY(
    { _Pragma("unroll")
      for (int r = 0; r < 16; r++) {
        unsigned key = keymap(pm[r * 256 + t] + pg[r * 256 + t]);
        v[r] = ((unsigned long long)key << 32) | (unsigned)(cb * EPB + r * 256 + t);
      } },
    { q[pos] = v[r]; })
}

__global__ void k_radix_scatter(const unsigned long long* __restrict__ src, unsigned long long* __restrict__ dst,
                                const unsigned* __restrict__ hist, int nper, int nblk, int shift) {
  int batch = blockIdx.x / nblk, cb = blockIdx.x % nblk;
  const unsigned long long* p = src + (size_t)batch * nper + (size_t)cb * EPB;
  unsigned long long* q = dst + (size_t)batch * nper;
  SCATTER_BODY(
    { _Pragma("unroll")
      for (int r = 0; r < 16; r++) v[r] = p[r * 256 + t]; },
    { q[pos] = v[r]; })
}

// last pass: write only the low 32 bits (the permutation index).
__global__ void k_radix_scatter_lo(const unsigned long long* __restrict__ src, unsigned* __restrict__ dst,
                                   const unsigned* __restrict__ hist, int nper, int nblk) {
  int batch = blockIdx.x / nblk, cb = blockIdx.x % nblk;
  const int shift = 56;
  const unsigned long long* p = src + (size_t)batch * nper + (size_t)cb * EPB;
  unsigned* q = dst + (size_t)batch * nper;
  SCATTER_BODY(
    { _Pragma("unroll")
      for (int r = 0; r < 16; r++) v[r] = p[r * 256 + t]; },
    { q[pos] = (unsigned)v[r]; })
}

// ---- Plackett-Luce: segmented reverse-cumlogsumexp ----
__global__ void kpl_seg(const float* __restrict__ logits, const unsigned* __restrict__ order,
                        int n, int nseg, float* __restrict__ segM, float* __restrict__ segT,
                        double* __restrict__ acc, int row) {
  int bs = blockIdx.x;
  int b = bs / nseg, seg = bs % nseg;
  int t = threadIdx.x;
  const float* lg = logits + (size_t)b * n;
  const unsigned* od = order + (size_t)b * n + (size_t)seg * LSEG;
  float s0 = lg[od[t * 2]], s1 = lg[od[t * 2 + 1]];
  float m = fmaxf(s0, s1);
  float T = expf(s0 - m) + expf(s1 - m);
  double ss = (double)s0 + (double)s1;
  __shared__ float sm[256], st_[256];
  __shared__ double sd[256];
  sm[t] = m; st_[t] = T; sd[t] = ss;
  __syncthreads();
  for (int off = 128; off > 0; off >>= 1) {
    if (t < off) { comb(sm[t], st_[t], sm[t + off], st_[t + off]); sd[t] += sd[t + off]; }
    __syncthreads();
  }
  if (t == 0) { segM[bs] = sm[0]; segT[bs] = st_[0]; atomicAdd(&acc[row * 8 + b], sd[0]); }
}

__global__ void __launch_bounds__(512) kpl_scan(const float* __restrict__ segM, const float* __restrict__ segT,
                                                int nseg, float* __restrict__ sufM, float* __restrict__ sufT) {
  int b = blockIdx.x, t = threadIdx.x;
  __shared__ float sm[512], st_[512];
  float M = -INFINITY, T = 0.f;
  if (t < nseg) { M = segM[b * nseg + t]; T = segT[b * nseg + t]; }
  sm[t] = M; st_[t] = T;
  __syncthreads();
  for (int off = 1; off < 512; off <<= 1) {
    float M2 = -INFINITY, T2 = 0.f;
    if (t + off < 512) { M2 = sm[t + off]; T2 = st_[t + off]; }
    __syncthreads();
    comb(M, T, M2, T2);
    sm[t] = M; st_[t] = T;
    __syncthreads();
  }
  if (t < nseg) {
    float eM = -INFINITY, eT = 0.f;
    if (t + 1 < nseg) { eM = sm[t + 1]; eT = st_[t + 1]; }
    sufM[b * nseg + t] = eM; sufT[b * nseg + t] = eT;
  }
}

__global__ void kpl_main(const float* __restrict__ logits, const unsigned* __restrict__ order,
                         int n, int nseg, const float* __restrict__ sufM, const float* __restrict__ sufT,
                         double* __restrict__ acc, int row) {
  int bs = blockIdx.x;
  int b = bs / nseg, seg = bs % nseg;
  int t = threadIdx.x;
  const float* lg = logits + (size_t)b * n;
  const unsigned* od = order + (size_t)b * n + (size_t)seg * LSEG;
  float s0 = lg[od[t * 2]], s1 = lg[od[t * 2 + 1]];
  float m = fmaxf(s0, s1);
  float T = expf(s0 - m) + expf(s1 - m);
  __shared__ float sm[256], st_[256];
  sm[t] = m; st_[t] = T;
  __syncthreads();
  float Mi = m, Ti = T;
  for (int off = 1; off < 256; off <<= 1) {
    float M2 = -INFINITY, T2 = 0.f;
    if (t + off < 256) { M2 = sm[t + off]; T2 = st_[t + off]; }
    __syncthreads();
    comb(Mi, Ti, M2, T2);
    sm[t] = Mi; st_[t] = Ti;
    __syncthreads();
  }
  float Mx = -INFINITY, Tx = 0.f;
  if (t + 1 < 256) { Mx = sm[t + 1]; Tx = st_[t + 1]; }
  comb(Mx, Tx, sufM[bs], sufT[bs]);
  double lsum = 0.0;
  {
    float s = s1;
    if (Tx == 0.f) { Mx = s; Tx = 1.f; }
    else if (s > Mx) { Tx = Tx * expf(Mx - s) + 1.f; Mx = s; }
    else Tx += expf(s - Mx);
    lsum += (double)Mx + (double)logf(Tx);
    s = s0;
    if (s > Mx) { Tx = Tx * expf(Mx - s) + 1.f; Mx = s; }
    else Tx += expf(s - Mx);
    lsum += (double)Mx + (double)logf(Tx);
  }
  __shared__ double sd[256];
  sd[t] = lsum;
  __syncthreads();
  for (int off = 128; off > 0; off >>= 1) { if (t < off) sd[t] += sd[t + off]; __syncthreads(); }
  if (t == 0) atomicAdd(&acc[row * 8 + b], -sd[0]);
}

// conv1 batched over 4 batches; mf layout [b4][addr][ch] -> 32B contiguous store per thread.
__global__ void k_conv1b(const unsigned* __restrict__ permg, const float* __restrict__ pmw,
                         const float* __restrict__ pmb, float* __restrict__ mf) {
  __shared__ float wl[216];
  __shared__ float bl[24];
  int t = threadIdx.x;
  for (int i = t; i < 216; i += 256) wl[i] = pmw[i];
  if (t < 24) bl[t] = pmb[t];
  __syncthreads();
  int b4 = blockIdx.x / NBLK_MEM;
  int g = (blockIdx.x % NBLK_MEM) * 256 + t;
  int mm = g >> 16, p = g & 65535;
  int i = p >> 8, j = p & 255;
  const unsigned* ad = permg + (size_t)b4 * NMEM + mm * 65536;
  float nb[3][3];
  #pragma unroll
  for (int di = 0; di < 3; di++)
    #pragma unroll
    for (int dj = 0; dj < 3; dj++) {
      int ii = i + di - 1, jj = j + dj - 1;
      nb[di][dj] = (ii >= 0 && ii < 256 && jj >= 0 && jj < 256) ? (float)ad[ii * 256 + jj] : 0.f;
    }
  unsigned c = ad[p];
  float o[8];
  #pragma unroll
  for (int oc = 0; oc < 8; oc++) {
    float s = bl[mm * 8 + oc];
    #pragma unroll
    for (int di = 0; di < 3; di++)
      #pragma unroll
      for (int dj = 0; dj < 3; dj++)
        s += wl[mm * 72 + oc * 9 + di * 3 + dj] * nb[di][dj];
    o[oc] = fmaxf(s, 0.f);
  }
  float4* dst = (float4*)(mf + ((size_t)b4 * NMEM + c) * 8);
  dst[0] = make_float4(o[0], o[1], o[2], o[3]);
  dst[1] = make_float4(o[4], o[5], o[6], o[7]);
}

// conv2: 4-row register tiling, sliding 3-row window (R4-proven math),
// __launch_bounds__(256,4) -> VGPR budget 128 so the 72-float window stays
// in registers (R4/R5 spilled because default target capped VGPR at 64).
#define LOADROW(DST, RR) do {                                                  \
    int rr_ = (RR);                                                            \
    if (rr_ >= 0 && rr_ < 24576) {                                             \
      _Pragma("unroll")                                                        \
      for (int dl = 0; dl < 3; dl++) {                                         \
        int ll = l + dl - 1;                                                   \
        if (ll >= 0 && ll < 8) {                                               \
          const float4* px = (const float4*)(base + ((size_t)rr_ * 8 + ll) * 8); \
          float4 a_ = px[0], b_ = px[1];                                       \
          DST[dl][0] = a_.x; DST[dl][1] = a_.y; DST[dl][2] = a_.z; DST[dl][3] = a_.w; \
          DST[dl][4] = b_.x; DST[dl][5] = b_.y; DST[dl][6] = b_.z; DST[dl][7] = b_.w; \
        } else {                                                               \
          _Pragma("unroll")                                                    \
          for (int c = 0; c < 8; c++) DST[dl][c] = 0.f;                        \
        }                                                                      \
      }                                                                        \
    } else {                                                                   \
      _Pragma("unroll")                                                        \
      for (int dl = 0; dl < 3; dl++)                                           \
        _Pragma("unroll")                                                      \
        for (int c = 0; c < 8; c++) DST[dl][c] = 0.f;                          \
    }                                                                          \
  } while (0)

#define STEP(TA, MI, BO) do {                                                  \
    _Pragma("unroll")                                                          \
    for (int c2 = 0; c2 < 16; c2++) {                                          \
      float s = bl2[c2];                                                       \
      _Pragma("unroll")                                                        \
      for (int c = 0; c < 8; c++) {                                            \
        const float* w = &wl[c2 * 72 + c * 9];                                 \
        s += w[0] * TA[0][c] + w[1] * TA[1][c] + w[2] * TA[2][c]               \
           + w[3] * MI[0][c] + w[4] * MI[1][c] + w[5] * MI[2][c]               \
           + w[6] * BO[0][c] + w[7] * BO[1][c] + w[8] * BO[2][c];              \
      }                                                                        \
      sum[c2] += fmaxf(s, 0.f);                                                \
    }                                                                          \
  } while (0)

__global__ void __launch_bounds__(256, 4)
k_conv2b(const float* __restrict__ mf, const float* __restrict__ mcw,
         const float* __restrict__ mcb, double* __restrict__ part, int gb) {
  __shared__ float wl[1152];
  __shared__ float bl2[16];
  __shared__ float pw[4][16][4];
  int t = threadIdx.x;
  for (int i = t; i < 1152; i += 256) wl[i] = mcw[i];
  if (t < 16) bl2[t] = mcb[t];
  __syncthreads();
  int b4 = blockIdx.x / NBLK2;
  int blk = blockIdx.x % NBLK2;
  int l = t & 7;
  int r0 = blk * 128 + (t >> 3) * 4;
  const float* base = mf + (size_t)b4 * (NMEM * 8);
  float nA[3][8], nB[3][8], nC[3][8];
  float sum[16];
  #pragma unroll
  for (int c2 = 0; c2 < 16; c2++) sum[c2] = 0.f;
  LOADROW(nA, r0 - 1);
  LOADROW(nB, r0);
  LOADROW(nC, r0 + 1); STEP(nA, nB, nC);
  LOADROW(nA, r0 + 2); STEP(nB, nC, nA);
  LOADROW(nB, r0 + 3); STEP(nC, nA, nB);
  LOADROW(nC, r0 + 4); STEP(nA, nB, nC);
  int lane = t & 63, wv = t >> 6;
  #pragma unroll
  for (int c2 = 0; c2 < 16; c2++) {
    float v = sum[c2];
    v += __shfl_xor(v, 1);
    v += __shfl_xor(v, 8);
    v += __shfl_xor(v, 16);
    v += __shfl_xor(v, 32);
    if ((lane & 1) == 0 && ((lane >> 3) & 7) == 0) pw[wv][c2][(lane & 7) >> 1] = v;
  }
  __syncthreads();
  if (t < 64) {
    int c2 = t >> 2, d = t & 3;
    double s = (double)pw[0][c2][d] + (double)pw[1][c2][d] + (double)pw[2][c2][d] + (double)pw[3][c2][d];
    part[((size_t)(gb + b4) * NBLK2 + blk) * 64 + t] = s;
  }
}

__global__ void k_pool_final(const double* __restrict__ part, double* __restrict__ pooled) {
  int b = blockIdx.x, t = threadIdx.x;
  int c2 = t >> 4, a = (t >> 2) & 3, d = t & 3;
  double s = 0.0;
  for (int j = 0; j < 48; j++)
    s += part[((size_t)b * NBLK2 + a * 48 + j) * 64 + c2 * 4 + d];
  pooled[b * 256 + t] = s / 12288.0;
}

__global__ void k_oplogits(const float* __restrict__ pjw, const float* __restrict__ pjb,
                           const double* __restrict__ pooled, const float* __restrict__ gop,
                           float* __restrict__ oplog, unsigned long long* __restrict__ opkv) {
  __shared__ double pl[8][256];
  int t = threadIdx.x;
  #pragma unroll
  for (int b = 0; b < 8; b++) pl[b][t] = pooled[b * 256 + t];
  __syncthreads();
  int k = blockIdx.x * 256 + t;
  const float4* row = (const float4*)(pjw + (size_t)k * 256);
  double acc[8];
  #pragma unroll
  for (int b = 0; b < 8; b++) acc[b] = 0.0;
  for (int j4 = 0; j4 < 64; j4++) {
    float4 w = row[j4];
    int j = j4 * 4;
    #pragma unroll
    for (int b = 0; b < 8; b++)
      acc[b] += (double)w.x * pl[b][j] + (double)w.y * pl[b][j + 1]
              + (double)w.z * pl[b][j + 2] + (double)w.w * pl[b][j + 3];
  }
  float bias = pjb[k];
  #pragma unroll
  for (int b = 0; b < 8; b++) {
    float ol = (float)(acc[b] + (double)bias);
    oplog[(size_t)b * NOP + k] = ol;
    float key = ol + gop[(size_t)b * NOP + k];
    opkv[(size_t)b * NOP + k] = ((unsigned long long)keymap(key) << 32) | (unsigned)k;
  }
}

static __device__ __forceinline__ float tierf(float h) {
  return h <= 2.f ? 1.f : (h <= 4.f ? 1.5f : (h <= 8.f ? 2.f : (h <= 16.f ? 3.f : 5.f)));
}
static __device__ __forceinline__ double penf(float d) {
  float fwd = d > 0.f ? d : 0.f;
  float bwd = d < 0.f ? -d : 0.f;
  return (double)(fwd * tierf(fwd)) + (double)(bwd * bwd * tierf(bwd));
}

// fused intra (row 1) + inter (row 0) penalties
__global__ void k_pen(const unsigned* __restrict__ perm, const unsigned* __restrict__ oo,
                      double* __restrict__ acc) {
  int g = blockIdx.x * 256 + threadIdx.x;
  int b = g >> 16, k = g & 65535;
  const unsigned* P = perm + (size_t)b * NMEM;
  float A = (float)P[k], Bv = (float)P[NOP + k], Cv = (float)P[2 * NOP + k];
  double pi = penf(Bv - A) + penf(Cv - Bv);
  double pe = 0.0;
  if (k < 65535) {
    unsigned k0 = oo[(size_t)b * NOP + k], k1 = oo[(size_t)b * NOP + k + 1];
    pe = penf((float)P[k1] - (float)P[2 * NOP + k0]);
  }
  __shared__ double ri[256], re[256];
  ri[threadIdx.x] = pi; re[threadIdx.x] = pe;
  __syncthreads();
  for (int off = 128; off > 0; off >>= 1) {
    if (threadIdx.x < off) { ri[threadIdx.x] += ri[threadIdx.x + off]; re[threadIdx.x] += re[threadIdx.x + off]; }
    __syncthreads();
  }
  if (threadIdx.x == 0) { atomicAdd(&acc[8 + b], ri[0]); atomicAdd(&acc[0 + b], re[0]); }
}

__global__ void k_finalize(const double* __restrict__ acc, float* __restrict__ out) {
  if (threadIdx.x < 32) out[threadIdx.x] = (float)acc[threadIdx.x];
}

extern "C" void kernel_launch(void* const* d_in, const int* in_sizes, int n_in,
                              void* d_out, int out_size, void* d_ws, size_t ws_size,
                              hipStream_t stream) {
  (void)in_sizes; (void)n_in; (void)out_size; (void)ws_size;
  const float* ml  = (const float*)d_in[0];
  const float* gm  = (const float*)d_in[1];
  const float* gop = (const float*)d_in[2];
  const float* pmw = (const float*)d_in[3];
  const float* pmb = (const float*)d_in[4];
  const float* mcw = (const float*)d_in[5];
  const float* mcb = (const float*)d_in[6];
  const float* pjw = (const float*)d_in[7];
  const float* pjb = (const float*)d_in[8];
  float* out = (float*)d_out;
  char* ws = (char*)d_ws;

  unsigned long long* kvA = (unsigned long long*)(ws + 0);          // 12,582,912
  unsigned long long* kvB = (unsigned long long*)(ws + 12582912);   // 12,582,912
  unsigned* hist   = (unsigned*)(ws + 25165824);                    //  <= 393,216
  unsigned* perm   = (unsigned*)(ws + 31457280);                    //  6,291,456
  double*   part   = (double*)(ws + 37748736);                      //    786,432
  double*   pooled = (double*)(ws + 40894464);
  double*   acc    = (double*)(ws + 40910848);
  float*    segM   = (float*)(ws + 40911104);
  float*    segT   = (float*)(ws + 40923392);
  float*    sufM   = (float*)(ws + 40935680);
  float*    sufT   = (float*)(ws + 40947968);
  float* mf = (float*)(ws + 0);                                     // conv phase reuse (25.1 MB)
  unsigned long long* opkvA = (unsigned long long*)(ws + 0);
  unsigned long long* opkvB = (unsigned long long*)(ws + 4194304);
  float*    oplog = (float*)(ws + 8388608);
  unsigned* oo    = (unsigned*)(ws + 10485760);

  k_zero<<<1, 32, 0, stream>>>(acc);

  // ---- mem argsort: pass0 builds keys on the fly; pass3 writes perm directly ----
  k_radix_hist0<<<NB * NC_MEM, 256, 0, stream>>>(ml, gm, hist);
  k_radix_scan<<<NB, 1024, 0, stream>>>(hist, 256 * NC_MEM);
  k_radix_scatter0<<<NB * NC_MEM, 256, 0, stream>>>(ml, gm, kvA, hist);
  k_radix_hist<<<NB * NC_MEM, 256, 0, stream>>>(kvA, hist, NMEM, NC_MEM, 40);
  k_radix_scan<<<NB, 1024, 0, stream>>>(hist, 256 * NC_MEM);
  k_radix_scatter<<<NB * NC_MEM, 256, 0, stream>>>(kvA, kvB, hist, NMEM, NC_MEM, 40);
  k_radix_hist<<<NB * NC_MEM, 256, 0, stream>>>(kvB, hist, NMEM, NC_MEM, 48);
  k_radix_scan<<<NB, 1024, 0, stream>>>(hist, 256 * NC_MEM);
  k_radix_scatter<<<NB * NC_MEM, 256, 0, stream>>>(kvB, kvA, hist, NMEM, NC_MEM, 48);
  k_radix_hist<<<NB * NC_MEM, 256, 0, stream>>>(kvA, hist, NMEM, NC_MEM, 56);
  k_radix_scan<<<NB, 1024, 0, stream>>>(hist, 256 * NC_MEM);
  k_radix_scatter_lo<<<NB * NC_MEM, 256, 0, stream>>>(kvA, perm, hist, NMEM, NC_MEM);

  // mem PL logprob (row 3)
  {
    int nseg = NMEM / LSEG;  // 384
    kpl_seg <<<NB * nseg, 256, 0, stream>>>(ml, perm, NMEM, nseg, segM, segT, acc, 3);
    kpl_scan<<<NB, 512, 0, stream>>>(segM, segT, nseg, sufM, sufT);
    kpl_main<<<NB * nseg, 256, 0, stream>>>(ml, perm, NMEM, nseg, sufM, sufT, acc, 3);
  }

  // ---- conv1 + conv2 + pooling, 2 groups of 4 batches ----
  for (int g = 0; g < 2; g++) {
    k_conv1b<<<4 * NBLK_MEM, 256, 0, stream>>>(perm + (size_t)g * 4 * NMEM, pmw, pmb, mf);
    k_conv2b<<<4 * NBLK2, 256, 0, stream>>>(mf, mcw, mcb, part, g * 4);
  }
  k_pool_final<<<NB, 256, 0, stream>>>(part, pooled);

  // ---- op logits + keys ----
  k_oplogits<<<NOP / 256, 256, 0, stream>>>(pjw, pjb, pooled, gop, oplog, opkvA);

  // ---- op argsort: pass3 writes oo directly ----
  k_radix_hist<<<NB * NC_OP, 256, 0, stream>>>(opkvA, hist, NOP, NC_OP, 32);
  k_radix_scan<<<NB, 1024, 0, stream>>>(hist, 256 * NC_OP);
  k_radix_scatter<<<NB * NC_OP, 256, 0, stream>>>(opkvA, opkvB, hist, NOP, NC_OP, 32);
  k_radix_hist<<<NB * NC_OP, 256, 0, stream>>>(opkvB, hist, NOP, NC_OP, 40);
  k_radix_scan<<<NB, 1024, 0, stream>>>(hist, 256 * NC_OP);
  k_radix_scatter<<<NB * NC_OP, 256, 0, stream>>>(opkvB, opkvA, hist, NOP, NC_OP, 40);
  k_radix_hist<<<NB * NC_OP, 256, 0, stream>>>(opkvA, hist, NOP, NC_OP, 48);
  k_radix_scan<<<NB, 1024, 0, stream>>>(hist, 256 * NC_OP);
  k_radix_scatter<<<NB * NC_OP, 256, 0, stream>>>(opkvA, opkvB, hist, NOP, NC_OP, 48);
  k_radix_hist<<<NB * NC_OP, 256, 0, stream>>>(opkvB, hist, NOP, NC_OP, 56);
  k_radix_scan<<<NB, 1024, 0, stream>>>(hist, 256 * NC_OP);
  k_radix_scatter_lo<<<NB * NC_OP, 256, 0, stream>>>(opkvB, oo, hist, NOP, NC_OP);

  // op PL logprob (row 2)
  {
    int nseg = NOP / LSEG;   // 128
    kpl_seg <<<NB * nseg, 256, 0, stream>>>(oplog, oo, NOP, nseg, segM, segT, acc, 2);
    kpl_scan<<<NB, 512, 0, stream>>>(segM, segT, nseg, sufM, sufT);
    kpl_main<<<NB * nseg, 256, 0, stream>>>(oplog, oo, NOP, nseg, sufM, sufT, acc, 2);
  }

  // penalties (rows 0,1)
  k_pen<<<NB * NOP / 256, 256, 0, stream>>>(perm, oo, acc);

  k_finalize<<<1, 32, 0, stream>>>(acc, out);
}

// Round 8
// 534.304 us; speedup vs baseline: 7.3229x; 7.3229x over previous
//
#include <hip/hip_runtime.h>
#include <math.h>

#define NB 8
#define NMEM 196608
#define NOP 65536
#define NBLK_MEM 768
#define LSEG 512
#define EPB 4096
#define NC_MEM 48   // NMEM / EPB
#define NC_OP 16    // NOP / EPB

static __device__ __forceinline__ unsigned keymap(float f) {
  unsigned u = __float_as_uint(f);
  return (u & 0x80000000u) ? ~u : (u | 0x80000000u);
}

// logsumexp state combiner: (M,T) represents M + log(T); T==0 is identity.
static __device__ __forceinline__ void comb(float& M1, float& T1, float M2, float T2) {
  if (T2 == 0.f) return;
  if (T1 == 0.f) { M1 = M2; T1 = T2; return; }
  float M = fmaxf(M1, M2);
  T1 = T1 * expf(M1 - M) + T2 * expf(M2 - M);
  M1 = M;
}

__global__ void k_zero(double* acc) {
  if (threadIdx.x < 32) acc[threadIdx.x] = 0.0;
}

// ---- radix sort: 4x8-bit passes, stable, 4096 elements/block ----
// pass 0 variants build keys on the fly from ml+gm (bit-exact same fp add).
__global__ void k_radix_hist0(const float* __restrict__ ml, const float* __restrict__ gm,
                              unsigned* __restrict__ hist) {
  __shared__ unsigned h[256];
  int batch = blockIdx.x / NC_MEM, cb = blockIdx.x % NC_MEM;
  int t = threadIdx.x;
  h[t] = 0;
  __syncthreads();
  const float* pm = ml + (size_t)batch * NMEM + (size_t)cb * EPB;
  const float* pg = gm + (size_t)batch * NMEM + (size_t)cb * EPB;
  #pragma unroll
  for (int r = 0; r < 16; r++) {
    unsigned key = keymap(pm[r * 256 + t] + pg[r * 256 + t]);
    atomicAdd(&h[key & 255u], 1u);
  }
  __syncthreads();
  hist[((size_t)batch * 256 + t) * NC_MEM + cb] = h[t];
}

__global__ void k_radix_hist(const unsigned long long* __restrict__ src, unsigned* __restrict__ hist,
                             int nper, int nblk, int shift) {
  __shared__ unsigned h[256];
  int batch = blockIdx.x / nblk, cb = blockIdx.x % nblk;
  int t = threadIdx.x;
  h[t] = 0;
  __syncthreads();
  const unsigned long long* p = src + (size_t)batch * nper + (size_t)cb * EPB;
  #pragma unroll
  for (int r = 0; r < 16; r++) {
    unsigned long long v = p[r * 256 + t];
    unsigned d = (unsigned)(v >> shift) & 255u;
    atomicAdd(&h[d], 1u);
  }
  __syncthreads();
  hist[((size_t)batch * 256 + t) * nblk + cb] = h[t];
}

__global__ void __launch_bounds__(1024) k_radix_scan(unsigned* __restrict__ hist, int L) {
  int b = blockIdx.x, t = threadIdx.x;
  unsigned* h = hist + (size_t)b * L;
  int C = L / 1024;
  unsigned s = 0;
  for (int i = 0; i < C; i++) s += h[t * C + i];
  __shared__ unsigned ls[1024];
  ls[t] = s;
  __syncthreads();
  for (int off = 1; off < 1024; off <<= 1) {
    unsigned add = (t >= off) ? ls[t - off] : 0u;
    __syncthreads();
    ls[t] += add;
    __syncthreads();
  }
  unsigned run = (t > 0) ? ls[t - 1] : 0u;
  for (int i = 0; i < C; i++) { unsigned v = h[t * C + i]; h[t * C + i] = run; run += v; }
}

// stable in-block rank: pos = base[d] + run[d] + wave-exclusive + ballot lane rank.
#define SCATTER_BODY(GETV, WRITE)                                              \
  __shared__ unsigned base[256];                                               \
  __shared__ unsigned run[256];                                                \
  __shared__ unsigned wh[4][256];                                              \
  int t = threadIdx.x, lane = t & 63, wv = t >> 6;                             \
  base[t] = hist[((size_t)batch * 256 + t) * nblk + cb];                       \
  run[t] = 0;                                                                  \
  unsigned long long v[16];                                                    \
  GETV;                                                                        \
  __syncthreads();                                                             \
  _Pragma("unroll")                                                            \
  for (int r = 0; r < 16; r++) {                                               \
    unsigned d = (unsigned)(v[r] >> shift) & 255u;                             \
    unsigned long long m = ~0ull;                                              \
    _Pragma("unroll")                                                          \
    for (int bit = 0; bit < 8; bit++) {                                        \
      unsigned long long bal = __ballot((d >> bit) & 1u);                      \
      m &= ((d >> bit) & 1u) ? bal : ~bal;                                     \
    }                                                                          \
    unsigned rank = (unsigned)__popcll(m & ((1ull << lane) - 1ull));           \
    _Pragma("unroll")                                                          \
    for (int w = 0; w < 4; w++) wh[w][t] = 0;                                  \
    __syncthreads();                                                           \
    if (rank == 0) wh[wv][d] = (unsigned)__popcll(m);                          \
    __syncthreads();                                                           \
    {                                                                          \
      unsigned run_t = run[t];                                                 \
      _Pragma("unroll")                                                        \
      for (int w = 0; w < 4; w++) { unsigned x = wh[w][t]; wh[w][t] = run_t; run_t += x; } \
      run[t] = run_t;                                                          \
    }                                                                          \
    __syncthreads();                                                           \
    unsigned pos = base[d] + wh[wv][d] + rank;                                 \
    WRITE;                                                                     \
    __syncthreads();                                                           \
  }

__global__ void k_radix_scatter0(const float* __restrict__ ml, const float* __restrict__ gm,
                                 unsigned long long* __restrict__ dst, const unsigned* __restrict__ hist) {
  int batch = blockIdx.x / NC_MEM, cb = blockIdx.x % NC_MEM;
  const int nblk = NC_MEM, shift = 32;
  const float* pm = ml + (size_t)batch * NMEM + (size_t)cb * EPB;
  const float* pg = gm + (size_t)batch * NMEM + (size_t)cb * EPB;
  unsigned long long* q = dst + (size_t)batch * NMEM;
  SCATTER_BODY(
    { _Pragma("unroll")
      for (int r = 0; r < 16; r++) {
        unsigned key = keymap(pm[r * 256 + t] + pg[r * 256 + t]);
        v[r] = ((unsigned long long)key << 32) | (unsigned)(cb * EPB + r * 256 + t);
      } },
    { q[pos] = v[r]; })
}

__global__ void k_radix_scatter(const unsigned long long* __restrict__ src, unsigned long long* __restrict__ dst,
                                const unsigned* __restrict__ hist, int nper, int nblk, int shift) {
  int batch = blockIdx.x / nblk, cb = blockIdx.x % nblk;
  const unsigned long long* p = src + (size_t)batch * nper + (size_t)cb * EPB;
  unsigned long long* q = dst + (size_t)batch * nper;
  SCATTER_BODY(
    { _Pragma("unroll")
      for (int r = 0; r < 16; r++) v[r] = p[r * 256 + t]; },
    { q[pos] = v[r]; })
}

// last pass: write only the low 32 bits (the permutation index).
__global__ void k_radix_scatter_lo(const unsigned long long* __restrict__ src, unsigned* __restrict__ dst,
                                   const unsigned* __restrict__ hist, int nper, int nblk) {
  int batch = blockIdx.x / nblk, cb = blockIdx.x % nblk;
  const int shift = 56;
  const unsigned long long* p = src + (size_t)batch * nper + (size_t)cb * EPB;
  unsigned* q = dst + (size_t)batch * nper;
  SCATTER_BODY(
    { _Pragma("unroll")
      for (int r = 0; r < 16; r++) v[r] = p[r * 256 + t]; },
    { q[pos] = (unsigned)v[r]; })
}

// ---- Plackett-Luce: segmented reverse-cumlogsumexp ----
__global__ void kpl_seg(const float* __restrict__ logits, const unsigned* __restrict__ order,
                        int n, int nseg, float* __restrict__ segM, float* __restrict__ segT,
                        double* __restrict__ acc, int row) {
  int bs = blockIdx.x;
  int b = bs / nseg, seg = bs % nseg;
  int t = threadIdx.x;
  const float* lg = logits + (size_t)b * n;
  const unsigned* od = order + (size_t)b * n + (size_t)seg * LSEG;
  float s0 = lg[od[t * 2]], s1 = lg[od[t * 2 + 1]];
  float m = fmaxf(s0, s1);
  float T = expf(s0 - m) + expf(s1 - m);
  double ss = (double)s0 + (double)s1;
  __shared__ float sm[256], st_[256];
  __shared__ double sd[256];
  sm[t] = m; st_[t] = T; sd[t] = ss;
  __syncthreads();
  for (int off = 128; off > 0; off >>= 1) {
    if (t < off) { comb(sm[t], st_[t], sm[t + off], st_[t + off]); sd[t] += sd[t + off]; }
    __syncthreads();
  }
  if (t == 0) { segM[bs] = sm[0]; segT[bs] = st_[0]; atomicAdd(&acc[row * 8 + b], sd[0]); }
}

__global__ void __launch_bounds__(512) kpl_scan(const float* __restrict__ segM, const float* __restrict__ segT,
                                                int nseg, float* __restrict__ sufM, float* __restrict__ sufT) {
  int b = blockIdx.x, t = threadIdx.x;
  __shared__ float sm[512], st_[512];
  float M = -INFINITY, T = 0.f;
  if (t < nseg) { M = segM[b * nseg + t]; T = segT[b * nseg + t]; }
  sm[t] = M; st_[t] = T;
  __syncthreads();
  for (int off = 1; off < 512; off <<= 1) {
    float M2 = -INFINITY, T2 = 0.f;
    if (t + off < 512) { M2 = sm[t + off]; T2 = st_[t + off]; }
    __syncthreads();
    comb(M, T, M2, T2);
    sm[t] = M; st_[t] = T;
    __syncthreads();
  }
  if (t < nseg) {
    float eM = -INFINITY, eT = 0.f;
    if (t + 1 < nseg) { eM = sm[t + 1]; eT = st_[t + 1]; }
    sufM[b * nseg + t] = eM; sufT[b * nseg + t] = eT;
  }
}

__global__ void kpl_main(const float* __restrict__ logits, const unsigned* __restrict__ order,
                         int n, int nseg, const float* __restrict__ sufM, const float* __restrict__ sufT,
                         double* __restrict__ acc, int row) {
  int bs = blockIdx.x;
  int b = bs / nseg, seg = bs % nseg;
  int t = threadIdx.x;
  const float* lg = logits + (size_t)b * n;
  const unsigned* od = order + (size_t)b * n + (size_t)seg * LSEG;
  float s0 = lg[od[t * 2]], s1 = lg[od[t * 2 + 1]];
  float m = fmaxf(s0, s1);
  float T = expf(s0 - m) + expf(s1 - m);
  __shared__ float sm[256], st_[256];
  sm[t] = m; st_[t] = T;
  __syncthreads();
  float Mi = m, Ti = T;
  for (int off = 1; off < 256; off <<= 1) {
    float M2 = -INFINITY, T2 = 0.f;
    if (t + off < 256) { M2 = sm[t + off]; T2 = st_[t + off]; }
    __syncthreads();
    comb(Mi, Ti, M2, T2);
    sm[t] = Mi; st_[t] = Ti;
    __syncthreads();
  }
  float Mx = -INFINITY, Tx = 0.f;
  if (t + 1 < 256) { Mx = sm[t + 1]; Tx = st_[t + 1]; }
  comb(Mx, Tx, sufM[bs], sufT[bs]);
  double lsum = 0.0;
  {
    float s = s1;
    if (Tx == 0.f) { Mx = s; Tx = 1.f; }
    else if (s > Mx) { Tx = Tx * expf(Mx - s) + 1.f; Mx = s; }
    else Tx += expf(s - Mx);
    lsum += (double)Mx + (double)logf(Tx);
    s = s0;
    if (s > Mx) { Tx = Tx * expf(Mx - s) + 1.f; Mx = s; }
    else Tx += expf(s - Mx);
    lsum += (double)Mx + (double)logf(Tx);
  }
  __shared__ double sd[256];
  sd[t] = lsum;
  __syncthreads();
  for (int off = 128; off > 0; off >>= 1) { if (t < off) sd[t] += sd[t + off]; __syncthreads(); }
  if (t == 0) atomicAdd(&acc[row * 8 + b], -sd[0]);
}

// conv1 batched over 4 batches; mf layout [b4][addr][ch] -> 32B contiguous store per thread.
__global__ void k_conv1b(const unsigned* __restrict__ permg, const float* __restrict__ pmw,
                         const float* __restrict__ pmb, float* __restrict__ mf) {
  __shared__ float wl[216];
  __shared__ float bl[24];
  int t = threadIdx.x;
  for (int i = t; i < 216; i += 256) wl[i] = pmw[i];
  if (t < 24) bl[t] = pmb[t];
  __syncthreads();
  int b4 = blockIdx.x / NBLK_MEM;
  int g = (blockIdx.x % NBLK_MEM) * 256 + t;
  int mm = g >> 16, p = g & 65535;
  int i = p >> 8, j = p & 255;
  const unsigned* ad = permg + (size_t)b4 * NMEM + mm * 65536;
  float nb[3][3];
  #pragma unroll
  for (int di = 0; di < 3; di++)
    #pragma unroll
    for (int dj = 0; dj < 3; dj++) {
      int ii = i + di - 1, jj = j + dj - 1;
      nb[di][dj] = (ii >= 0 && ii < 256 && jj >= 0 && jj < 256) ? (float)ad[ii * 256 + jj] : 0.f;
    }
  unsigned c = ad[p];
  float o[8];
  #pragma unroll
  for (int oc = 0; oc < 8; oc++) {
    float s = bl[mm * 8 + oc];
    #pragma unroll
    for (int di = 0; di < 3; di++)
      #pragma unroll
      for (int dj = 0; dj < 3; dj++)
        s += wl[mm * 72 + oc * 9 + di * 3 + dj] * nb[di][dj];
    o[oc] = fmaxf(s, 0.f);
  }
  float4* dst = (float4*)(mf + ((size_t)b4 * NMEM + c) * 8);
  dst[0] = make_float4(o[0], o[1], o[2], o[3]);
  dst[1] = make_float4(o[4], o[5], o[6], o[7]);
}

// conv2: R3 thread=pixel consume structure, but input tile staged in LDS.
// Stage rows r0-1..r0+32 (34 rows x 64 floats, row stride 68 -> conflict-free
// optimal b128 reads). Out-of-range rows staged as zeros (bit-identical to
// the global-load bounds checks). Consume loop identical to R3 (VGPR ~48).
__global__ void k_conv2b(const float* __restrict__ mf, const float* __restrict__ mcw,
                         const float* __restrict__ mcb, double* __restrict__ part, int gb) {
  __shared__ float wl[1152];
  __shared__ float bl2[16];
  __shared__ float pw[4][16][4];
  __shared__ float tile[34 * 68];   // 9248 B, 16B-aligned rows (68*4=272 B)
  int t = threadIdx.x;
  for (int i = t; i < 1152; i += 256) wl[i] = mcw[i];
  if (t < 16) bl2[t] = mcb[t];
  int b4 = blockIdx.x / NBLK_MEM;
  int blk = blockIdx.x % NBLK_MEM;
  int r0 = blk * 32;
  const float* base = mf + (size_t)b4 * (NMEM * 8);
  // stage: 34 rows x 16 float4 = 544 float4 across 256 threads
  for (int i = t; i < 34 * 16; i += 256) {
    int row = i >> 4, f4 = i & 15;
    int gr = r0 - 1 + row;
    float4 val = make_float4(0.f, 0.f, 0.f, 0.f);
    if (gr >= 0 && gr < 24576)
      val = ((const float4*)(base + (size_t)gr * 64))[f4];
    *((float4*)&tile[row * 68 + f4 * 4]) = val;
  }
  __syncthreads();
  int rl = (t >> 3) + 1;            // local row in tile (global row r0 + (t>>3))
  int l = t & 7;
  float nb[9][8];
  #pragma unroll
  for (int q = 0; q < 9; q++) {
    int dr = q / 3 - 1, dl = q % 3 - 1;
    int ll = l + dl;
    if (ll >= 0 && ll < 8) {
      const float4* px = (const float4*)&tile[(rl + dr) * 68 + ll * 8];
      float4 a = px[0], bb = px[1];
      nb[q][0] = a.x; nb[q][1] = a.y; nb[q][2] = a.z; nb[q][3] = a.w;
      nb[q][4] = bb.x; nb[q][5] = bb.y; nb[q][6] = bb.z; nb[q][7] = bb.w;
    } else {
      #pragma unroll
      for (int c = 0; c < 8; c++) nb[q][c] = 0.f;
    }
  }
  int lane = t & 63, wv = t >> 6;
  #pragma unroll
  for (int c2 = 0; c2 < 16; c2++) {
    float s = bl2[c2];
    #pragma unroll
    for (int c = 0; c < 8; c++)
      #pragma unroll
      for (int q = 0; q < 9; q++)
        s += wl[c2 * 72 + c * 9 + q] * nb[q][c];
    float v = fmaxf(s, 0.f);
    v += __shfl_xor(v, 1);
    v += __shfl_xor(v, 8);
    v += __shfl_xor(v, 16);
    v += __shfl_xor(v, 32);
    if ((lane & 1) == 0 && ((t >> 3) & 7) == 0) pw[wv][c2][(lane & 7) >> 1] = v;
  }
  __syncthreads();
  if (t < 64) {
    int c2 = t >> 2, d = t & 3;
    double s = (double)pw[0][c2][d] + (double)pw[1][c2][d] + (double)pw[2][c2][d] + (double)pw[3][c2][d];
    part[((size_t)(gb + b4) * NBLK_MEM + blk) * 64 + t] = s;
  }
}

__global__ void k_pool_final(const double* __restrict__ part, double* __restrict__ pooled) {
  int b = blockIdx.x, t = threadIdx.x;       // t = c2*16 + a*4 + d
  int c2 = t >> 4, a = (t >> 2) & 3, d = t & 3;
  double s = 0.0;
  for (int j = 0; j < 192; j++)
    s += part[((size_t)b * NBLK_MEM + a * 192 + j) * 64 + c2 * 4 + d];
  pooled[b * 256 + t] = s / 12288.0;
}

__global__ void k_oplogits(const float* __restrict__ pjw, const float* __restrict__ pjb,
                           const double* __restrict__ pooled, const float* __restrict__ gop,
                           float* __restrict__ oplog, unsigned long long* __restrict__ opkv) {
  __shared__ double pl[8][256];
  int t = threadIdx.x;
  #pragma unroll
  for (int b = 0; b < 8; b++) pl[b][t] = pooled[b * 256 + t];
  __syncthreads();
  int k = blockIdx.x * 256 + t;
  const float4* row = (const float4*)(pjw + (size_t)k * 256);
  double acc[8];
  #pragma unroll
  for (int b = 0; b < 8; b++) acc[b] = 0.0;
  for (int j4 = 0; j4 < 64; j4++) {
    float4 w = row[j4];
    int j = j4 * 4;
    #pragma unroll
    for (int b = 0; b < 8; b++)
      acc[b] += (double)w.x * pl[b][j] + (double)w.y * pl[b][j + 1]
              + (double)w.z * pl[b][j + 2] + (double)w.w * pl[b][j + 3];
  }
  float bias = pjb[k];
  #pragma unroll
  for (int b = 0; b < 8; b++) {
    float ol = (float)(acc[b] + (double)bias);
    oplog[(size_t)b * NOP + k] = ol;
    float key = ol + gop[(size_t)b * NOP + k];
    opkv[(size_t)b * NOP + k] = ((unsigned long long)keymap(key) << 32) | (unsigned)k;
  }
}

static __device__ __forceinline__ float tierf(float h) {
  return h <= 2.f ? 1.f : (h <= 4.f ? 1.5f : (h <= 8.f ? 2.f : (h <= 16.f ? 3.f : 5.f)));
}
static __device__ __forceinline__ double penf(float d) {
  float fwd = d > 0.f ? d : 0.f;
  float bwd = d < 0.f ? -d : 0.f;
  return (double)(fwd * tierf(fwd)) + (double)(bwd * bwd * tierf(bwd));
}

// fused intra (row 1) + inter (row 0) penalties
__global__ void k_pen(const unsigned* __restrict__ perm, const unsigned* __restrict__ oo,
                      double* __restrict__ acc) {
  int g = blockIdx.x * 256 + threadIdx.x;
  int b = g >> 16, k = g & 65535;
  const unsigned* P = perm + (size_t)b * NMEM;
  float A = (float)P[k], Bv = (float)P[NOP + k], Cv = (float)P[2 * NOP + k];
  double pi = penf(Bv - A) + penf(Cv - Bv);
  double pe = 0.0;
  if (k < 65535) {
    unsigned k0 = oo[(size_t)b * NOP + k], k1 = oo[(size_t)b * NOP + k + 1];
    pe = penf((float)P[k1] - (float)P[2 * NOP + k0]);
  }
  __shared__ double ri[256], re[256];
  ri[threadIdx.x] = pi; re[threadIdx.x] = pe;
  __syncthreads();
  for (int off = 128; off > 0; off >>= 1) {
    if (threadIdx.x < off) { ri[threadIdx.x] += ri[threadIdx.x + off]; re[threadIdx.x] += re[threadIdx.x + off]; }
    __syncthreads();
  }
  if (threadIdx.x == 0) { atomicAdd(&acc[8 + b], ri[0]); atomicAdd(&acc[0 + b], re[0]); }
}

__global__ void k_finalize(const double* __restrict__ acc, float* __restrict__ out) {
  if (threadIdx.x < 32) out[threadIdx.x] = (float)acc[threadIdx.x];
}

extern "C" void kernel_launch(void* const* d_in, const int* in_sizes, int n_in,
                              void* d_out, int out_size, void* d_ws, size_t ws_size,
                              hipStream_t stream) {
  (void)in_sizes; (void)n_in; (void)out_size; (void)ws_size;
  const float* ml  = (const float*)d_in[0];
  const float* gm  = (const float*)d_in[1];
  const float* gop = (const float*)d_in[2];
  const float* pmw = (const float*)d_in[3];
  const float* pmb = (const float*)d_in[4];
  const float* mcw = (const float*)d_in[5];
  const float* mcb = (const float*)d_in[6];
  const float* pjw = (const float*)d_in[7];
  const float* pjb = (const float*)d_in[8];
  float* out = (float*)d_out;
  char* ws = (char*)d_ws;

  unsigned long long* kvA = (unsigned long long*)(ws + 0);          // 12,582,912
  unsigned long long* kvB = (unsigned long long*)(ws + 12582912);   // 12,582,912
  unsigned* hist   = (unsigned*)(ws + 25165824);                    //  <= 393,216
  unsigned* perm   = (unsigned*)(ws + 31457280);                    //  6,291,456
  double*   part   = (double*)(ws + 37748736);                      //  3,145,728
  double*   pooled = (double*)(ws + 40894464);
  double*   acc    = (double*)(ws + 40910848);
  float*    segM   = (float*)(ws + 40911104);
  float*    segT   = (float*)(ws + 40923392);
  float*    sufM   = (float*)(ws + 40935680);
  float*    sufT   = (float*)(ws + 40947968);
  float* mf = (float*)(ws + 0);                                     // conv phase reuse (25.1 MB)
  unsigned long long* opkvA = (unsigned long long*)(ws + 0);
  unsigned long long* opkvB = (unsigned long long*)(ws + 4194304);
  float*    oplog = (float*)(ws + 8388608);
  unsigned* oo    = (unsigned*)(ws + 10485760);

  k_zero<<<1, 32, 0, stream>>>(acc);

  // ---- mem argsort: pass0 builds keys on the fly; pass3 writes perm directly ----
  k_radix_hist0<<<NB * NC_MEM, 256, 0, stream>>>(ml, gm, hist);
  k_radix_scan<<<NB, 1024, 0, stream>>>(hist, 256 * NC_MEM);
  k_radix_scatter0<<<NB * NC_MEM, 256, 0, stream>>>(ml, gm, kvA, hist);
  k_radix_hist<<<NB * NC_MEM, 256, 0, stream>>>(kvA, hist, NMEM, NC_MEM, 40);
  k_radix_scan<<<NB, 1024, 0, stream>>>(hist, 256 * NC_MEM);
  k_radix_scatter<<<NB * NC_MEM, 256, 0, stream>>>(kvA, kvB, hist, NMEM, NC_MEM, 40);
  k_radix_hist<<<NB * NC_MEM, 256, 0, stream>>>(kvB, hist, NMEM, NC_MEM, 48);
  k_radix_scan<<<NB, 1024, 0, stream>>>(hist, 256 * NC_MEM);
  k_radix_scatter<<<NB * NC_MEM, 256, 0, stream>>>(kvB, kvA, hist, NMEM, NC_MEM, 48);
  k_radix_hist<<<NB * NC_MEM, 256, 0, stream>>>(kvA, hist, NMEM, NC_MEM, 56);
  k_radix_scan<<<NB, 1024, 0, stream>>>(hist, 256 * NC_MEM);
  k_radix_scatter_lo<<<NB * NC_MEM, 256, 0, stream>>>(kvA, perm, hist, NMEM, NC_MEM);

  // mem PL logprob (row 3)
  {
    int nseg = NMEM / LSEG;  // 384
    kpl_seg <<<NB * nseg, 256, 0, stream>>>(ml, perm, NMEM, nseg, segM, segT, acc, 3);
    kpl_scan<<<NB, 512, 0, stream>>>(segM, segT, nseg, sufM, sufT);
    kpl_main<<<NB * nseg, 256, 0, stream>>>(ml, perm, NMEM, nseg, sufM, sufT, acc, 3);
  }

  // ---- conv1 + conv2 + pooling, 2 groups of 4 batches ----
  for (int g = 0; g < 2; g++) {
    k_conv1b<<<4 * NBLK_MEM, 256, 0, stream>>>(perm + (size_t)g * 4 * NMEM, pmw, pmb, mf);
    k_conv2b<<<4 * NBLK_MEM, 256, 0, stream>>>(mf, mcw, mcb, part, g * 4);
  }
  k_pool_final<<<NB, 256, 0, stream>>>(part, pooled);

  // ---- op logits + keys ----
  k_oplogits<<<NOP / 256, 256, 0, stream>>>(pjw, pjb, pooled, gop, oplog, opkvA);

  // ---- op argsort: pass3 writes oo directly ----
  k_radix_hist<<<NB * NC_OP, 256, 0, stream>>>(opkvA, hist, NOP, NC_OP, 32);
  k_radix_scan<<<NB, 1024, 0, stream>>>(hist, 256 * NC_OP);
  k_radix_scatter<<<NB * NC_OP, 256, 0, stream>>>(opkvA, opkvB, hist, NOP, NC_OP, 32);
  k_radix_hist<<<NB * NC_OP, 256, 0, stream>>>(opkvB, hist, NOP, NC_OP, 40);
  k_radix_scan<<<NB, 1024, 0, stream>>>(hist, 256 * NC_OP);
  k_radix_scatter<<<NB * NC_OP, 256, 0, stream>>>(opkvB, opkvA, hist, NOP, NC_OP, 40);
  k_radix_hist<<<NB * NC_OP, 256, 0, stream>>>(opkvA, hist, NOP, NC_OP, 48);
  k_radix_scan<<<NB, 1024, 0, stream>>>(hist, 256 * NC_OP);
  k_radix_scatter<<<NB * NC_OP, 256, 0, stream>>>(opkvA, opkvB, hist, NOP, NC_OP, 48);
  k_radix_hist<<<NB * NC_OP, 256, 0, stream>>>(opkvB, hist, NOP, NC_OP, 56);
  k_radix_scan<<<NB, 1024, 0, stream>>>(hist, 256 * NC_OP);
  k_radix_scatter_lo<<<NB * NC_OP, 256, 0, stream>>>(opkvB, oo, hist, NOP, NC_OP);

  // op PL logprob (row 2)
  {
    int nseg = NOP / LSEG;   // 128
    kpl_seg <<<NB * nseg, 256, 0, stream>>>(oplog, oo, NOP, nseg, segM, segT, acc, 2);
    kpl_scan<<<NB, 512, 0, stream>>>(segM, segT, nseg, sufM, sufT);
    kpl_main<<<NB * nseg, 256, 0, stream>>>(oplog, oo, NOP, nseg, sufM, sufT, acc, 2);
  }

  // penalties (rows 0,1)
  k_pen<<<NB * NOP / 256, 256, 0, stream>>>(perm, oo, acc);

  k_finalize<<<1, 32, 0, stream>>>(acc, out);
}

// Round 9
// 508.999 us; speedup vs baseline: 7.6869x; 1.0497x over previous
//
#include <hip/hip_runtime.h>
#include <math.h>

#define NB 8
#define NMEM 196608
#define NOP 65536
#define NBLK_MEM 768
#define LSEG 512
#define EPB 4096
#define NC_MEM 48   // NMEM / EPB
#define NC_OP 16    // NOP / EPB

static __device__ __forceinline__ unsigned keymap(float f) {
  unsigned u = __float_as_uint(f);
  return (u & 0x80000000u) ? ~u : (u | 0x80000000u);
}

// logsumexp state combiner: (M,T) represents M + log(T); T==0 is identity.
static __device__ __forceinline__ void comb(float& M1, float& T1, float M2, float T2) {
  if (T2 == 0.f) return;
  if (T1 == 0.f) { M1 = M2; T1 = T2; return; }
  float M = fmaxf(M1, M2);
  T1 = T1 * expf(M1 - M) + T2 * expf(M2 - M);
  M1 = M;
}

__global__ void k_zero(double* acc) {
  if (threadIdx.x < 32) acc[threadIdx.x] = 0.0;
}

// ---- radix sort: 4x8-bit passes, stable, 4096 elements/block ----
// pass 0 variants build keys on the fly from ml+gm (bit-exact same fp add).
__global__ void k_radix_hist0(const float* __restrict__ ml, const float* __restrict__ gm,
                              unsigned* __restrict__ hist) {
  __shared__ unsigned h[256];
  int batch = blockIdx.x / NC_MEM, cb = blockIdx.x % NC_MEM;
  int t = threadIdx.x;
  h[t] = 0;
  __syncthreads();
  const float* pm = ml + (size_t)batch * NMEM + (size_t)cb * EPB;
  const float* pg = gm + (size_t)batch * NMEM + (size_t)cb * EPB;
  #pragma unroll
  for (int r = 0; r < 16; r++) {
    unsigned key = keymap(pm[r * 256 + t] + pg[r * 256 + t]);
    atomicAdd(&h[key & 255u], 1u);
  }
  __syncthreads();
  hist[((size_t)batch * 256 + t) * NC_MEM + cb] = h[t];
}

__global__ void k_radix_hist(const unsigned long long* __restrict__ src, unsigned* __restrict__ hist,
                             int nper, int nblk, int shift) {
  __shared__ unsigned h[256];
  int batch = blockIdx.x / nblk, cb = blockIdx.x % nblk;
  int t = threadIdx.x;
  h[t] = 0;
  __syncthreads();
  const unsigned long long* p = src + (size_t)batch * nper + (size_t)cb * EPB;
  #pragma unroll
  for (int r = 0; r < 16; r++) {
    unsigned long long v = p[r * 256 + t];
    unsigned d = (unsigned)(v >> shift) & 255u;
    atomicAdd(&h[d], 1u);
  }
  __syncthreads();
  hist[((size_t)batch * 256 + t) * nblk + cb] = h[t];
}

__global__ void __launch_bounds__(1024) k_radix_scan(unsigned* __restrict__ hist, int L) {
  int b = blockIdx.x, t = threadIdx.x;
  unsigned* h = hist + (size_t)b * L;
  int C = L / 1024;
  unsigned s = 0;
  for (int i = 0; i < C; i++) s += h[t * C + i];
  __shared__ unsigned ls[1024];
  ls[t] = s;
  __syncthreads();
  for (int off = 1; off < 1024; off <<= 1) {
    unsigned add = (t >= off) ? ls[t - off] : 0u;
    __syncthreads();
    ls[t] += add;
    __syncthreads();
  }
  unsigned run = (t > 0) ? ls[t - 1] : 0u;
  for (int i = 0; i < C; i++) { unsigned v = h[t * C + i]; h[t * C + i] = run; run += v; }
}

// stable in-block rank: pos = base[d] + run[d] + wave-exclusive + ballot lane rank.
#define SCATTER_BODY(GETV, WRITE)                                              \
  __shared__ unsigned base[256];                                               \
  __shared__ unsigned run[256];                                                \
  __shared__ unsigned wh[4][256];                                              \
  int t = threadIdx.x, lane = t & 63, wv = t >> 6;                             \
  base[t] = hist[((size_t)batch * 256 + t) * nblk + cb];                       \
  run[t] = 0;                                                                  \
  unsigned long long v[16];                                                    \
  GETV;                                                                        \
  __syncthreads();                                                             \
  _Pragma("unroll")                                                            \
  for (int r = 0; r < 16; r++) {                                               \
    unsigned d = (unsigned)(v[r] >> shift) & 255u;                             \
    unsigned long long m = ~0ull;                                              \
    _Pragma("unroll")                                                          \
    for (int bit = 0; bit < 8; bit++) {                                        \
      unsigned long long bal = __ballot((d >> bit) & 1u);                      \
      m &= ((d >> bit) & 1u) ? bal : ~bal;                                     \
    }                                                                          \
    unsigned rank = (unsigned)__popcll(m & ((1ull << lane) - 1ull));           \
    _Pragma("unroll")                                                          \
    for (int w = 0; w < 4; w++) wh[w][t] = 0;                                  \
    __syncthreads();                                                           \
    if (rank == 0) wh[wv][d] = (unsigned)__popcll(m);                          \
    __syncthreads();                                                           \
    {                                                                          \
      unsigned run_t = run[t];                                                 \
      _Pragma("unroll")                                                        \
      for (int w = 0; w < 4; w++) { unsigned x = wh[w][t]; wh[w][t] = run_t; run_t += x; } \
      run[t] = run_t;                                                          \
    }                                                                          \
    __syncthreads();                                                           \
    unsigned pos = base[d] + wh[wv][d] + rank;                                 \
    WRITE;                                                                     \
    __syncthreads();                                                           \
  }

__global__ void k_radix_scatter0(const float* __restrict__ ml, const float* __restrict__ gm,
                                 unsigned long long* __restrict__ dst, const unsigned* __restrict__ hist) {
  int batch = blockIdx.x / NC_MEM, cb = blockIdx.x % NC_MEM;
  const int nblk = NC_MEM, shift = 32;
  const float* pm = ml + (size_t)batch * NMEM + (size_t)cb * EPB;
  const float* pg = gm + (size_t)batch * NMEM + (size_t)cb * EPB;
  unsigned long long* q = dst + (size_t)batch * NMEM;
  SCATTER_BODY(
    { _Pragma("unroll")
      for (int r = 0; r < 16; r++) {
        unsigned key = keymap(pm[r * 256 + t] + pg[r * 256 + t]);
        v[r] = ((unsigned long long)key << 32) | (unsigned)(cb * EPB + r * 256 + t);
      } },
    { q[pos] = v[r]; })
}

__global__ void k_radix_scatter(const unsigned long long* __restrict__ src, unsigned long long* __restrict__ dst,
                                const unsigned* __restrict__ hist, int nper, int nblk, int shift) {
  int batch = blockIdx.x / nblk, cb = blockIdx.x % nblk;
  const unsigned long long* p = src + (size_t)batch * nper + (size_t)cb * EPB;
  unsigned long long* q = dst + (size_t)batch * nper;
  SCATTER_BODY(
    { _Pragma("unroll")
      for (int r = 0; r < 16; r++) v[r] = p[r * 256 + t]; },
    { q[pos] = v[r]; })
}

// last pass: write only the low 32 bits (the permutation index).
__global__ void k_radix_scatter_lo(const unsigned long long* __restrict__ src, unsigned* __restrict__ dst,
                                   const unsigned* __restrict__ hist, int nper, int nblk) {
  int batch = blockIdx.x / nblk, cb = blockIdx.x % nblk;
  const int shift = 56;
  const unsigned long long* p = src + (size_t)batch * nper + (size_t)cb * EPB;
  unsigned* q = dst + (size_t)batch * nper;
  SCATTER_BODY(
    { _Pragma("unroll")
      for (int r = 0; r < 16; r++) v[r] = p[r * 256 + t]; },
    { q[pos] = (unsigned)v[r]; })
}

// ---- Plackett-Luce: segmented reverse-cumlogsumexp ----
__global__ void kpl_seg(const float* __restrict__ logits, const unsigned* __restrict__ order,
                        int n, int nseg, float* __restrict__ segM, float* __restrict__ segT,
                        double* __restrict__ acc, int row) {
  int bs = blockIdx.x;
  int b = bs / nseg, seg = bs % nseg;
  int t = threadIdx.x;
  const float* lg = logits + (size_t)b * n;
  const unsigned* od = order + (size_t)b * n + (size_t)seg * LSEG;
  float s0 = lg[od[t * 2]], s1 = lg[od[t * 2 + 1]];
  float m = fmaxf(s0, s1);
  float T = expf(s0 - m) + expf(s1 - m);
  double ss = (double)s0 + (double)s1;
  __shared__ float sm[256], st_[256];
  __shared__ double sd[256];
  sm[t] = m; st_[t] = T; sd[t] = ss;
  __syncthreads();
  for (int off = 128; off > 0; off >>= 1) {
    if (t < off) { comb(sm[t], st_[t], sm[t + off], st_[t + off]); sd[t] += sd[t + off]; }
    __syncthreads();
  }
  if (t == 0) { segM[bs] = sm[0]; segT[bs] = st_[0]; atomicAdd(&acc[row * 8 + b], sd[0]); }
}

__global__ void __launch_bounds__(512) kpl_scan(const float* __restrict__ segM, const float* __restrict__ segT,
                                                int nseg, float* __restrict__ sufM, float* __restrict__ sufT) {
  int b = blockIdx.x, t = threadIdx.x;
  __shared__ float sm[512], st_[512];
  float M = -INFINITY, T = 0.f;
  if (t < nseg) { M = segM[b * nseg + t]; T = segT[b * nseg + t]; }
  sm[t] = M; st_[t] = T;
  __syncthreads();
  for (int off = 1; off < 512; off <<= 1) {
    float M2 = -INFINITY, T2 = 0.f;
    if (t + off < 512) { M2 = sm[t + off]; T2 = st_[t + off]; }
    __syncthreads();
    comb(M, T, M2, T2);
    sm[t] = M; st_[t] = T;
    __syncthreads();
  }
  if (t < nseg) {
    float eM = -INFINITY, eT = 0.f;
    if (t + 1 < nseg) { eM = sm[t + 1]; eT = st_[t + 1]; }
    sufM[b * nseg + t] = eM; sufT[b * nseg + t] = eT;
  }
}

__global__ void kpl_main(const float* __restrict__ logits, const unsigned* __restrict__ order,
                         int n, int nseg, const float* __restrict__ sufM, const float* __restrict__ sufT,
                         double* __restrict__ acc, int row) {
  int bs = blockIdx.x;
  int b = bs / nseg, seg = bs % nseg;
  int t = threadIdx.x;
  const float* lg = logits + (size_t)b * n;
  const unsigned* od = order + (size_t)b * n + (size_t)seg * LSEG;
  float s0 = lg[od[t * 2]], s1 = lg[od[t * 2 + 1]];
  float m = fmaxf(s0, s1);
  float T = expf(s0 - m) + expf(s1 - m);
  __shared__ float sm[256], st_[256];
  sm[t] = m; st_[t] = T;
  __syncthreads();
  float Mi = m, Ti = T;
  for (int off = 1; off < 256; off <<= 1) {
    float M2 = -INFINITY, T2 = 0.f;
    if (t + off < 256) { M2 = sm[t + off]; T2 = st_[t + off]; }
    __syncthreads();
    comb(Mi, Ti, M2, T2);
    sm[t] = Mi; st_[t] = Ti;
    __syncthreads();
  }
  float Mx = -INFINITY, Tx = 0.f;
  if (t + 1 < 256) { Mx = sm[t + 1]; Tx = st_[t + 1]; }
  comb(Mx, Tx, sufM[bs], sufT[bs]);
  double lsum = 0.0;
  {
    float s = s1;
    if (Tx == 0.f) { Mx = s; Tx = 1.f; }
    else if (s > Mx) { Tx = Tx * expf(Mx - s) + 1.f; Mx = s; }
    else Tx += expf(s - Mx);
    lsum += (double)Mx + (double)logf(Tx);
    s = s0;
    if (s > Mx) { Tx = Tx * expf(Mx - s) + 1.f; Mx = s; }
    else Tx += expf(s - Mx);
    lsum += (double)Mx + (double)logf(Tx);
  }
  __shared__ double sd[256];
  sd[t] = lsum;
  __syncthreads();
  for (int off = 128; off > 0; off >>= 1) { if (t < off) sd[t] += sd[t + off]; __syncthreads(); }
  if (t == 0) atomicAdd(&acc[row * 8 + b], -sd[0]);
}

// conv1 batched over 4 batches; mm is block-uniform (derived from blockIdx only)
// so weight/bias reads are scalar (s_load via constant cache), not LDS/VALU.
__global__ void k_conv1b(const unsigned* __restrict__ permg, const float* __restrict__ pmw,
                         const float* __restrict__ pmb, float* __restrict__ mf) {
  int t = threadIdx.x;
  int b4 = blockIdx.x / NBLK_MEM;
  int g0 = (blockIdx.x % NBLK_MEM) * 256;     // block-uniform
  int mm = g0 >> 16;                          // uniform: blocks never straddle 65536
  int p = (g0 & 65535) + t;
  int i = p >> 8, j = p & 255;
  const unsigned* ad = permg + (size_t)b4 * NMEM + mm * 65536;
  float nb[3][3];
  #pragma unroll
  for (int di = 0; di < 3; di++)
    #pragma unroll
    for (int dj = 0; dj < 3; dj++) {
      int ii = i + di - 1, jj = j + dj - 1;
      nb[di][dj] = (ii >= 0 && ii < 256 && jj >= 0 && jj < 256) ? (float)ad[ii * 256 + jj] : 0.f;
    }
  unsigned c = ad[p];
  float o[8];
  #pragma unroll
  for (int oc = 0; oc < 8; oc++) {
    float s = pmb[mm * 8 + oc];
    #pragma unroll
    for (int di = 0; di < 3; di++)
      #pragma unroll
      for (int dj = 0; dj < 3; dj++)
        s += pmw[mm * 72 + oc * 9 + di * 3 + dj] * nb[di][dj];
    o[oc] = fmaxf(s, 0.f);
  }
  float4* dst = (float4*)(mf + ((size_t)b4 * NMEM + c) * 8);
  dst[0] = make_float4(o[0], o[1], o[2], o[3]);
  dst[1] = make_float4(o[4], o[5], o[6], o[7]);
}

// conv2 (R3 structure, global nb loads = cache hits), weights/bias read directly
// from global with compile-time-constant indices -> scalar loads, freeing the
// DS/VALU pipes (was 1152 ds_read_b32/thread for weights).
__global__ void k_conv2b(const float* __restrict__ mf, const float* __restrict__ mcw,
                         const float* __restrict__ mcb, double* __restrict__ part, int gb) {
  __shared__ float pw[4][16][4];
  int t = threadIdx.x;
  int b4 = blockIdx.x / NBLK_MEM;
  int blk = blockIdx.x % NBLK_MEM;
  int r = blk * 32 + (t >> 3);
  int l = t & 7;
  const float* base = mf + (size_t)b4 * (NMEM * 8);
  float nb[9][8];
  #pragma unroll
  for (int q = 0; q < 9; q++) {
    int rr = r + q / 3 - 1, ll = l + q % 3 - 1;
    if (rr >= 0 && rr < 24576 && ll >= 0 && ll < 8) {
      const float4* px = (const float4*)(base + ((size_t)rr * 8 + ll) * 8);
      float4 a = px[0], bb = px[1];
      nb[q][0] = a.x; nb[q][1] = a.y; nb[q][2] = a.z; nb[q][3] = a.w;
      nb[q][4] = bb.x; nb[q][5] = bb.y; nb[q][6] = bb.z; nb[q][7] = bb.w;
    } else {
      #pragma unroll
      for (int c = 0; c < 8; c++) nb[q][c] = 0.f;
    }
  }
  int lane = t & 63, wv = t >> 6;
  #pragma unroll
  for (int c2 = 0; c2 < 16; c2++) {
    float s = mcb[c2];
    #pragma unroll
    for (int c = 0; c < 8; c++)
      #pragma unroll
      for (int q = 0; q < 9; q++)
        s += mcw[c2 * 72 + c * 9 + q] * nb[q][c];
    float v = fmaxf(s, 0.f);
    v += __shfl_xor(v, 1);
    v += __shfl_xor(v, 8);
    v += __shfl_xor(v, 16);
    v += __shfl_xor(v, 32);
    if ((lane & 1) == 0 && ((t >> 3) & 7) == 0) pw[wv][c2][(lane & 7) >> 1] = v;
  }
  __syncthreads();
  if (t < 64) {
    int c2 = t >> 2, d = t & 3;
    double s = (double)pw[0][c2][d] + (double)pw[1][c2][d] + (double)pw[2][c2][d] + (double)pw[3][c2][d];
    part[((size_t)(gb + b4) * NBLK_MEM + blk) * 64 + t] = s;
  }
}

__global__ void k_pool_final(const double* __restrict__ part, double* __restrict__ pooled) {
  int b = blockIdx.x, t = threadIdx.x;       // t = c2*16 + a*4 + d
  int c2 = t >> 4, a = (t >> 2) & 3, d = t & 3;
  double s = 0.0;
  for (int j = 0; j < 192; j++)
    s += part[((size_t)b * NBLK_MEM + a * 192 + j) * 64 + c2 * 4 + d];
  pooled[b * 256 + t] = s / 12288.0;
}

__global__ void k_oplogits(const float* __restrict__ pjw, const float* __restrict__ pjb,
                           const double* __restrict__ pooled, const float* __restrict__ gop,
                           float* __restrict__ oplog, unsigned long long* __restrict__ opkv) {
  __shared__ double pl[8][256];
  int t = threadIdx.x;
  #pragma unroll
  for (int b = 0; b < 8; b++) pl[b][t] = pooled[b * 256 + t];
  __syncthreads();
  int k = blockIdx.x * 256 + t;
  const float4* row = (const float4*)(pjw + (size_t)k * 256);
  double acc[8];
  #pragma unroll
  for (int b = 0; b < 8; b++) acc[b] = 0.0;
  for (int j4 = 0; j4 < 64; j4++) {
    float4 w = row[j4];
    int j = j4 * 4;
    #pragma unroll
    for (int b = 0; b < 8; b++)
      acc[b] += (double)w.x * pl[b][j] + (double)w.y * pl[b][j + 1]
              + (double)w.z * pl[b][j + 2] + (double)w.w * pl[b][j + 3];
  }
  float bias = pjb[k];
  #pragma unroll
  for (int b = 0; b < 8; b++) {
    float ol = (float)(acc[b] + (double)bias);
    oplog[(size_t)b * NOP + k] = ol;
    float key = ol + gop[(size_t)b * NOP + k];
    opkv[(size_t)b * NOP + k] = ((unsigned long long)keymap(key) << 32) | (unsigned)k;
  }
}

static __device__ __forceinline__ float tierf(float h) {
  return h <= 2.f ? 1.f : (h <= 4.f ? 1.5f : (h <= 8.f ? 2.f : (h <= 16.f ? 3.f : 5.f)));
}
static __device__ __forceinline__ double penf(float d) {
  float fwd = d > 0.f ? d : 0.f;
  float bwd = d < 0.f ? -d : 0.f;
  return (double)(fwd * tierf(fwd)) + (double)(bwd * bwd * tierf(bwd));
}

// fused intra (row 1) + inter (row 0) penalties
__global__ void k_pen(const unsigned* __restrict__ perm, const unsigned* __restrict__ oo,
                      double* __restrict__ acc) {
  int g = blockIdx.x * 256 + threadIdx.x;
  int b = g >> 16, k = g & 65535;
  const unsigned* P = perm + (size_t)b * NMEM;
  float A = (float)P[k], Bv = (float)P[NOP + k], Cv = (float)P[2 * NOP + k];
  double pi = penf(Bv - A) + penf(Cv - Bv);
  double pe = 0.0;
  if (k < 65535) {
    unsigned k0 = oo[(size_t)b * NOP + k], k1 = oo[(size_t)b * NOP + k + 1];
    pe = penf((float)P[k1] - (float)P[2 * NOP + k0]);
  }
  __shared__ double ri[256], re[256];
  ri[threadIdx.x] = pi; re[threadIdx.x] = pe;
  __syncthreads();
  for (int off = 128; off > 0; off >>= 1) {
    if (threadIdx.x < off) { ri[threadIdx.x] += ri[threadIdx.x + off]; re[threadIdx.x] += re[threadIdx.x + off]; }
    __syncthreads();
  }
  if (threadIdx.x == 0) { atomicAdd(&acc[8 + b], ri[0]); atomicAdd(&acc[0 + b], re[0]); }
}

__global__ void k_finalize(const double* __restrict__ acc, float* __restrict__ out) {
  if (threadIdx.x < 32) out[threadIdx.x] = (float)acc[threadIdx.x];
}

extern "C" void kernel_launch(void* const* d_in, const int* in_sizes, int n_in,
                              void* d_out, int out_size, void* d_ws, size_t ws_size,
                              hipStream_t stream) {
  (void)in_sizes; (void)n_in; (void)out_size; (void)ws_size;
  const float* ml  = (const float*)d_in[0];
  const float* gm  = (const float*)d_in[1];
  const float* gop = (const float*)d_in[2];
  const float* pmw = (const float*)d_in[3];
  const float* pmb = (const float*)d_in[4];
  const float* mcw = (const float*)d_in[5];
  const float* mcb = (const float*)d_in[6];
  const float* pjw = (const float*)d_in[7];
  const float* pjb = (const float*)d_in[8];
  float* out = (float*)d_out;
  char* ws = (char*)d_ws;

  unsigned long long* kvA = (unsigned long long*)(ws + 0);          // 12,582,912
  unsigned long long* kvB = (unsigned long long*)(ws + 12582912);   // 12,582,912
  unsigned* hist   = (unsigned*)(ws + 25165824);                    //  <= 393,216
  unsigned* perm   = (unsigned*)(ws + 31457280);                    //  6,291,456
  double*   part   = (double*)(ws + 37748736);                      //  3,145,728
  double*   pooled = (double*)(ws + 40894464);
  double*   acc    = (double*)(ws + 40910848);
  float*    segM   = (float*)(ws + 40911104);
  float*    segT   = (float*)(ws + 40923392);
  float*    sufM   = (float*)(ws + 40935680);
  float*    sufT   = (float*)(ws + 40947968);
  float* mf = (float*)(ws + 0);                                     // conv phase reuse (25.1 MB)
  unsigned long long* opkvA = (unsigned long long*)(ws + 0);
  unsigned long long* opkvB = (unsigned long long*)(ws + 4194304);
  float*    oplog = (float*)(ws + 8388608);
  unsigned* oo    = (unsigned*)(ws + 10485760);

  k_zero<<<1, 32, 0, stream>>>(acc);

  // ---- mem argsort: pass0 builds keys on the fly; pass3 writes perm directly ----
  k_radix_hist0<<<NB * NC_MEM, 256, 0, stream>>>(ml, gm, hist);
  k_radix_scan<<<NB, 1024, 0, stream>>>(hist, 256 * NC_MEM);
  k_radix_scatter0<<<NB * NC_MEM, 256, 0, stream>>>(ml, gm, kvA, hist);
  k_radix_hist<<<NB * NC_MEM, 256, 0, stream>>>(kvA, hist, NMEM, NC_MEM, 40);
  k_radix_scan<<<NB, 1024, 0, stream>>>(hist, 256 * NC_MEM);
  k_radix_scatter<<<NB * NC_MEM, 256, 0, stream>>>(kvA, kvB, hist, NMEM, NC_MEM, 40);
  k_radix_hist<<<NB * NC_MEM, 256, 0, stream>>>(kvB, hist, NMEM, NC_MEM, 48);
  k_radix_scan<<<NB, 1024, 0, stream>>>(hist, 256 * NC_MEM);
  k_radix_scatter<<<NB * NC_MEM, 256, 0, stream>>>(kvB, kvA, hist, NMEM, NC_MEM, 48);
  k_radix_hist<<<NB * NC_MEM, 256, 0, stream>>>(kvA, hist, NMEM, NC_MEM, 56);
  k_radix_scan<<<NB, 1024, 0, stream>>>(hist, 256 * NC_MEM);
  k_radix_scatter_lo<<<NB * NC_MEM, 256, 0, stream>>>(kvA, perm, hist, NMEM, NC_MEM);

  // mem PL logprob (row 3)
  {
    int nseg = NMEM / LSEG;  // 384
    kpl_seg <<<NB * nseg, 256, 0, stream>>>(ml, perm, NMEM, nseg, segM, segT, acc, 3);
    kpl_scan<<<NB, 512, 0, stream>>>(segM, segT, nseg, sufM, sufT);
    kpl_main<<<NB * nseg, 256, 0, stream>>>(ml, perm, NMEM, nseg, sufM, sufT, acc, 3);
  }

  // ---- conv1 + conv2 + pooling, 2 groups of 4 batches ----
  for (int g = 0; g < 2; g++) {
    k_conv1b<<<4 * NBLK_MEM, 256, 0, stream>>>(perm + (size_t)g * 4 * NMEM, pmw, pmb, mf);
    k_conv2b<<<4 * NBLK_MEM, 256, 0, stream>>>(mf, mcw, mcb, part, g * 4);
  }
  k_pool_final<<<NB, 256, 0, stream>>>(part, pooled);

  // ---- op logits + keys ----
  k_oplogits<<<NOP / 256, 256, 0, stream>>>(pjw, pjb, pooled, gop, oplog, opkvA);

  // ---- op argsort: pass3 writes oo directly ----
  k_radix_hist<<<NB * NC_OP, 256, 0, stream>>>(opkvA, hist, NOP, NC_OP, 32);
  k_radix_scan<<<NB, 1024, 0, stream>>>(hist, 256 * NC_OP);
  k_radix_scatter<<<NB * NC_OP, 256, 0, stream>>>(opkvA, opkvB, hist, NOP, NC_OP, 32);
  k_radix_hist<<<NB * NC_OP, 256, 0, stream>>>(opkvB, hist, NOP, NC_OP, 40);
  k_radix_scan<<<NB, 1024, 0, stream>>>(hist, 256 * NC_OP);
  k_radix_scatter<<<NB * NC_OP, 256, 0, stream>>>(opkvB, opkvA, hist, NOP, NC_OP, 40);
  k_radix_hist<<<NB * NC_OP, 256, 0, stream>>>(opkvA, hist, NOP, NC_OP, 48);
  k_radix_scan<<<NB, 1024, 0, stream>>>(hist, 256 * NC_OP);
  k_radix_scatter<<<NB * NC_OP, 256, 0, stream>>>(opkvA, opkvB, hist, NOP, NC_OP, 48);
  k_radix_hist<<<NB * NC_OP, 256, 0, stream>>>(opkvB, hist, NOP, NC_OP, 56);
  k_radix_scan<<<NB, 1024, 0, stream>>>(hist, 256 * NC_OP);
  k_radix_scatter_lo<<<NB * NC_OP, 256, 0, stream>>>(opkvB, oo, hist, NOP, NC_OP);

  // op PL logprob (row 2)
  {
    int nseg = NOP / LSEG;   // 128
    kpl_seg <<<NB * nseg, 256, 0, stream>>>(oplog, oo, NOP, nseg, segM, segT, acc, 2);
    kpl_scan<<<NB, 512, 0, stream>>>(segM, segT, nseg, sufM, sufT);
    kpl_main<<<NB * nseg, 256, 0, stream>>>(oplog, oo, NOP, nseg, sufM, sufT, acc, 2);
  }

  // penalties (rows 0,1)
  k_pen<<<NB * NOP / 256, 256, 0, stream>>>(perm, oo, acc);

  k_finalize<<<1, 32, 0, stream>>>(acc, out);
}

// Round 10
// 508.280 us; speedup vs baseline: 7.6978x; 1.0014x over previous
//
#include <hip/hip_runtime.h>
#include <math.h>

#define NB 8
#define NMEM 196608
#define NOP 65536
#define NBLK_MEM 768
#define LSEG 512
#define EPB 4096
#define NC_MEM 48   // NMEM / EPB
#define NC_OP 16    // NOP / EPB

static __device__ __forceinline__ unsigned keymap(float f) {
  unsigned u = __float_as_uint(f);
  return (u & 0x80000000u) ? ~u : (u | 0x80000000u);
}

// logsumexp state combiner: (M,T) represents M + log(T); T==0 is identity.
static __device__ __forceinline__ void comb(float& M1, float& T1, float M2, float T2) {
  if (T2 == 0.f) return;
  if (T1 == 0.f) { M1 = M2; T1 = T2; return; }
  float M = fmaxf(M1, M2);
  T1 = T1 * expf(M1 - M) + T2 * expf(M2 - M);
  M1 = M;
}

__global__ void k_zero(double* acc) {
  if (threadIdx.x < 32) acc[threadIdx.x] = 0.0;
}

// ---- radix sort: 4x8-bit passes, stable, 4096 elements/block ----
// pass 0 variants build keys on the fly from ml+gm (bit-exact same fp add).
__global__ void k_radix_hist0(const float* __restrict__ ml, const float* __restrict__ gm,
                              unsigned* __restrict__ hist) {
  __shared__ unsigned h[256];
  int batch = blockIdx.x / NC_MEM, cb = blockIdx.x % NC_MEM;
  int t = threadIdx.x;
  h[t] = 0;
  __syncthreads();
  const float* pm = ml + (size_t)batch * NMEM + (size_t)cb * EPB;
  const float* pg = gm + (size_t)batch * NMEM + (size_t)cb * EPB;
  #pragma unroll
  for (int r = 0; r < 16; r++) {
    unsigned key = keymap(pm[r * 256 + t] + pg[r * 256 + t]);
    atomicAdd(&h[key & 255u], 1u);
  }
  __syncthreads();
  hist[((size_t)batch * 256 + t) * NC_MEM + cb] = h[t];
}

__global__ void k_radix_hist(const unsigned long long* __restrict__ src, unsigned* __restrict__ hist,
                             int nper, int nblk, int shift) {
  __shared__ unsigned h[256];
  int batch = blockIdx.x / nblk, cb = blockIdx.x % nblk;
  int t = threadIdx.x;
  h[t] = 0;
  __syncthreads();
  const unsigned long long* p = src + (size_t)batch * nper + (size_t)cb * EPB;
  #pragma unroll
  for (int r = 0; r < 16; r++) {
    unsigned long long v = p[r * 256 + t];
    unsigned d = (unsigned)(v >> shift) & 255u;
    atomicAdd(&h[d], 1u);
  }
  __syncthreads();
  hist[((size_t)batch * 256 + t) * nblk + cb] = h[t];
}

__global__ void __launch_bounds__(1024) k_radix_scan(unsigned* __restrict__ hist, int L) {
  int b = blockIdx.x, t = threadIdx.x;
  unsigned* h = hist + (size_t)b * L;
  int C = L / 1024;
  unsigned s = 0;
  for (int i = 0; i < C; i++) s += h[t * C + i];
  __shared__ unsigned ls[1024];
  ls[t] = s;
  __syncthreads();
  for (int off = 1; off < 1024; off <<= 1) {
    unsigned add = (t >= off) ? ls[t - off] : 0u;
    __syncthreads();
    ls[t] += add;
    __syncthreads();
  }
  unsigned run = (t > 0) ? ls[t - 1] : 0u;
  for (int i = 0; i < C; i++) { unsigned v = h[t * C + i]; h[t * C + i] = run; run += v; }
}

// stable in-block rank: pos = base[d] + run[d] + wave-exclusive + ballot lane rank.
#define SCATTER_BODY(GETV, WRITE)                                              \
  __shared__ unsigned base[256];                                               \
  __shared__ unsigned run[256];                                                \
  __shared__ unsigned wh[4][256];                                              \
  int t = threadIdx.x, lane = t & 63, wv = t >> 6;                             \
  base[t] = hist[((size_t)batch * 256 + t) * nblk + cb];                       \
  run[t] = 0;                                                                  \
  unsigned long long v[16];                                                    \
  GETV;                                                                        \
  __syncthreads();                                                             \
  _Pragma("unroll")                                                            \
  for (int r = 0; r < 16; r++) {                                               \
    unsigned d = (unsigned)(v[r] >> shift) & 255u;                             \
    unsigned long long m = ~0ull;                                              \
    _Pragma("unroll")                                                          \
    for (int bit = 0; bit < 8; bit++) {                                        \
      unsigned long long bal = __ballot((d >> bit) & 1u);                      \
      m &= ((d >> bit) & 1u) ? bal : ~bal;                                     \
    }                                                                          \
    unsigned rank = (unsigned)__popcll(m & ((1ull << lane) - 1ull));           \
    _Pragma("unroll")                                                          \
    for (int w = 0; w < 4; w++) wh[w][t] = 0;                                  \
    __syncthreads();                                                           \
    if (rank == 0) wh[wv][d] = (unsigned)__popcll(m);                          \
    __syncthreads();                                                           \
    {                                                                          \
      unsigned run_t = run[t];                                                 \
      _Pragma("unroll")                                                        \
      for (int w = 0; w < 4; w++) { unsigned x = wh[w][t]; wh[w][t] = run_t; run_t += x; } \
      run[t] = run_t;                                                          \
    }                                                                          \
    __syncthreads();                                                           \
    unsigned pos = base[d] + wh[wv][d] + rank;                                 \
    WRITE;                                                                     \
    __syncthreads();                                                           \
  }

__global__ void k_radix_scatter0(const float* __restrict__ ml, const float* __restrict__ gm,
                                 unsigned long long* __restrict__ dst, const unsigned* __restrict__ hist) {
  int batch = blockIdx.x / NC_MEM, cb = blockIdx.x % NC_MEM;
  const int nblk = NC_MEM, shift = 32;
  const float* pm = ml + (size_t)batch * NMEM + (size_t)cb * EPB;
  const float* pg = gm + (size_t)batch * NMEM + (size_t)cb * EPB;
  unsigned long long* q = dst + (size_t)batch * NMEM;
  SCATTER_BODY(
    { _Pragma("unroll")
      for (int r = 0; r < 16; r++) {
        unsigned key = keymap(pm[r * 256 + t] + pg[r * 256 + t]);
        v[r] = ((unsigned long long)key << 32) | (unsigned)(cb * EPB + r * 256 + t);
      } },
    { q[pos] = v[r]; })
}

__global__ void k_radix_scatter(const unsigned long long* __restrict__ src, unsigned long long* __restrict__ dst,
                                const unsigned* __restrict__ hist, int nper, int nblk, int shift) {
  int batch = blockIdx.x / nblk, cb = blockIdx.x % nblk;
  const unsigned long long* p = src + (size_t)batch * nper + (size_t)cb * EPB;
  unsigned long long* q = dst + (size_t)batch * nper;
  SCATTER_BODY(
    { _Pragma("unroll")
      for (int r = 0; r < 16; r++) v[r] = p[r * 256 + t]; },
    { q[pos] = v[r]; })
}

// last pass: write only the low 32 bits (the permutation index).
__global__ void k_radix_scatter_lo(const unsigned long long* __restrict__ src, unsigned* __restrict__ dst,
                                   const unsigned* __restrict__ hist, int nper, int nblk) {
  int batch = blockIdx.x / nblk, cb = blockIdx.x % nblk;
  const int shift = 56;
  const unsigned long long* p = src + (size_t)batch * nper + (size_t)cb * EPB;
  unsigned* q = dst + (size_t)batch * nper;
  SCATTER_BODY(
    { _Pragma("unroll")
      for (int r = 0; r < 16; r++) v[r] = p[r * 256 + t]; },
    { q[pos] = (unsigned)v[r]; })
}

// ---- Plackett-Luce: segmented reverse-cumlogsumexp ----
// Pass 1 gathers logits[order] ONCE and stores them contiguous (slog) for pass 3.
__global__ void kpl_seg(const float* __restrict__ logits, const unsigned* __restrict__ order,
                        int n, int nseg, float* __restrict__ segM, float* __restrict__ segT,
                        float* __restrict__ slog, double* __restrict__ acc, int row) {
  int bs = blockIdx.x;
  int b = bs / nseg, seg = bs % nseg;
  int t = threadIdx.x;
  const float* lg = logits + (size_t)b * n;
  const unsigned* od = order + (size_t)b * n + (size_t)seg * LSEG;
  float s0 = lg[od[t * 2]], s1 = lg[od[t * 2 + 1]];
  *((float2*)&slog[(size_t)b * n + (size_t)seg * LSEG + t * 2]) = make_float2(s0, s1);
  float m = fmaxf(s0, s1);
  float T = expf(s0 - m) + expf(s1 - m);
  double ss = (double)s0 + (double)s1;
  __shared__ float sm[256], st_[256];
  __shared__ double sd[256];
  sm[t] = m; st_[t] = T; sd[t] = ss;
  __syncthreads();
  for (int off = 128; off > 0; off >>= 1) {
    if (t < off) { comb(sm[t], st_[t], sm[t + off], st_[t + off]); sd[t] += sd[t + off]; }
    __syncthreads();
  }
  if (t == 0) { segM[bs] = sm[0]; segT[bs] = st_[0]; atomicAdd(&acc[row * 8 + b], sd[0]); }
}

__global__ void __launch_bounds__(512) kpl_scan(const float* __restrict__ segM, const float* __restrict__ segT,
                                                int nseg, float* __restrict__ sufM, float* __restrict__ sufT) {
  int b = blockIdx.x, t = threadIdx.x;
  __shared__ float sm[512], st_[512];
  float M = -INFINITY, T = 0.f;
  if (t < nseg) { M = segM[b * nseg + t]; T = segT[b * nseg + t]; }
  sm[t] = M; st_[t] = T;
  __syncthreads();
  for (int off = 1; off < 512; off <<= 1) {
    float M2 = -INFINITY, T2 = 0.f;
    if (t + off < 512) { M2 = sm[t + off]; T2 = st_[t + off]; }
    __syncthreads();
    comb(M, T, M2, T2);
    sm[t] = M; st_[t] = T;
    __syncthreads();
  }
  if (t < nseg) {
    float eM = -INFINITY, eT = 0.f;
    if (t + 1 < nseg) { eM = sm[t + 1]; eT = st_[t + 1]; }
    sufM[b * nseg + t] = eM; sufT[b * nseg + t] = eT;
  }
}

// Pass 3 reads slog coalesced (no re-gather).
__global__ void kpl_main(const float* __restrict__ slog, int n, int nseg,
                         const float* __restrict__ sufM, const float* __restrict__ sufT,
                         double* __restrict__ acc, int row) {
  int bs = blockIdx.x;
  int b = bs / nseg, seg = bs % nseg;
  int t = threadIdx.x;
  float2 s01 = *((const float2*)&slog[(size_t)b * n + (size_t)seg * LSEG + t * 2]);
  float s0 = s01.x, s1 = s01.y;
  float m = fmaxf(s0, s1);
  float T = expf(s0 - m) + expf(s1 - m);
  __shared__ float sm[256], st_[256];
  sm[t] = m; st_[t] = T;
  __syncthreads();
  float Mi = m, Ti = T;
  for (int off = 1; off < 256; off <<= 1) {
    float M2 = -INFINITY, T2 = 0.f;
    if (t + off < 256) { M2 = sm[t + off]; T2 = st_[t + off]; }
    __syncthreads();
    comb(Mi, Ti, M2, T2);
    sm[t] = Mi; st_[t] = Ti;
    __syncthreads();
  }
  float Mx = -INFINITY, Tx = 0.f;
  if (t + 1 < 256) { Mx = sm[t + 1]; Tx = st_[t + 1]; }
  comb(Mx, Tx, sufM[bs], sufT[bs]);
  double lsum = 0.0;
  {
    float s = s1;
    if (Tx == 0.f) { Mx = s; Tx = 1.f; }
    else if (s > Mx) { Tx = Tx * expf(Mx - s) + 1.f; Mx = s; }
    else Tx += expf(s - Mx);
    lsum += (double)Mx + (double)logf(Tx);
    s = s0;
    if (s > Mx) { Tx = Tx * expf(Mx - s) + 1.f; Mx = s; }
    else Tx += expf(s - Mx);
    lsum += (double)Mx + (double)logf(Tx);
  }
  __shared__ double sd[256];
  sd[t] = lsum;
  __syncthreads();
  for (int off = 128; off > 0; off >>= 1) { if (t < off) sd[t] += sd[t + off]; __syncthreads(); }
  if (t == 0) atomicAdd(&acc[row * 8 + b], -sd[0]);
}

// conv1 batched over 4 batches; mm is block-uniform (derived from blockIdx only)
// so weight/bias reads are scalar (s_load via constant cache), not LDS/VALU.
__global__ void k_conv1b(const unsigned* __restrict__ permg, const float* __restrict__ pmw,
                         const float* __restrict__ pmb, float* __restrict__ mf) {
  int t = threadIdx.x;
  int b4 = blockIdx.x / NBLK_MEM;
  int g0 = (blockIdx.x % NBLK_MEM) * 256;     // block-uniform
  int mm = g0 >> 16;                          // uniform: blocks never straddle 65536
  int p = (g0 & 65535) + t;
  int i = p >> 8, j = p & 255;
  const unsigned* ad = permg + (size_t)b4 * NMEM + mm * 65536;
  float nb[3][3];
  #pragma unroll
  for (int di = 0; di < 3; di++)
    #pragma unroll
    for (int dj = 0; dj < 3; dj++) {
      int ii = i + di - 1, jj = j + dj - 1;
      nb[di][dj] = (ii >= 0 && ii < 256 && jj >= 0 && jj < 256) ? (float)ad[ii * 256 + jj] : 0.f;
    }
  unsigned c = ad[p];
  float o[8];
  #pragma unroll
  for (int oc = 0; oc < 8; oc++) {
    float s = pmb[mm * 8 + oc];
    #pragma unroll
    for (int di = 0; di < 3; di++)
      #pragma unroll
      for (int dj = 0; dj < 3; dj++)
        s += pmw[mm * 72 + oc * 9 + di * 3 + dj] * nb[di][dj];
    o[oc] = fmaxf(s, 0.f);
  }
  float4* dst = (float4*)(mf + ((size_t)b4 * NMEM + c) * 8);
  dst[0] = make_float4(o[0], o[1], o[2], o[3]);
  dst[1] = make_float4(o[4], o[5], o[6], o[7]);
}

// conv2 (R3 structure, global nb loads = cache hits), weights/bias read directly
// from global with compile-time-constant indices -> scalar loads.
__global__ void k_conv2b(const float* __restrict__ mf, const float* __restrict__ mcw,
                         const float* __restrict__ mcb, double* __restrict__ part, int gb) {
  __shared__ float pw[4][16][4];
  int t = threadIdx.x;
  int b4 = blockIdx.x / NBLK_MEM;
  int blk = blockIdx.x % NBLK_MEM;
  int r = blk * 32 + (t >> 3);
  int l = t & 7;
  const float* base = mf + (size_t)b4 * (NMEM * 8);
  float nb[9][8];
  #pragma unroll
  for (int q = 0; q < 9; q++) {
    int rr = r + q / 3 - 1, ll = l + q % 3 - 1;
    if (rr >= 0 && rr < 24576 && ll >= 0 && ll < 8) {
      const float4* px = (const float4*)(base + ((size_t)rr * 8 + ll) * 8);
      float4 a = px[0], bb = px[1];
      nb[q][0] = a.x; nb[q][1] = a.y; nb[q][2] = a.z; nb[q][3] = a.w;
      nb[q][4] = bb.x; nb[q][5] = bb.y; nb[q][6] = bb.z; nb[q][7] = bb.w;
    } else {
      #pragma unroll
      for (int c = 0; c < 8; c++) nb[q][c] = 0.f;
    }
  }
  int lane = t & 63, wv = t >> 6;
  #pragma unroll
  for (int c2 = 0; c2 < 16; c2++) {
    float s = mcb[c2];
    #pragma unroll
    for (int c = 0; c < 8; c++)
      #pragma unroll
      for (int q = 0; q < 9; q++)
        s += mcw[c2 * 72 + c * 9 + q] * nb[q][c];
    float v = fmaxf(s, 0.f);
    v += __shfl_xor(v, 1);
    v += __shfl_xor(v, 8);
    v += __shfl_xor(v, 16);
    v += __shfl_xor(v, 32);
    if ((lane & 1) == 0 && ((t >> 3) & 7) == 0) pw[wv][c2][(lane & 7) >> 1] = v;
  }
  __syncthreads();
  if (t < 64) {
    int c2 = t >> 2, d = t & 3;
    double s = (double)pw[0][c2][d] + (double)pw[1][c2][d] + (double)pw[2][c2][d] + (double)pw[3][c2][d];
    part[((size_t)(gb + b4) * NBLK_MEM + blk) * 64 + t] = s;
  }
}

__global__ void k_pool_final(const double* __restrict__ part, double* __restrict__ pooled) {
  int b = blockIdx.x, t = threadIdx.x;       // t = c2*16 + a*4 + d
  int c2 = t >> 4, a = (t >> 2) & 3, d = t & 3;
  double s = 0.0;
  for (int j = 0; j < 192; j++)
    s += part[((size_t)b * NBLK_MEM + a * 192 + j) * 64 + c2 * 4 + d];
  pooled[b * 256 + t] = s / 12288.0;
}

__global__ void k_oplogits(const float* __restrict__ pjw, const float* __restrict__ pjb,
                           const double* __restrict__ pooled, const float* __restrict__ gop,
                           float* __restrict__ oplog, unsigned long long* __restrict__ opkv) {
  __shared__ double pl[8][256];
  int t = threadIdx.x;
  #pragma unroll
  for (int b = 0; b < 8; b++) pl[b][t] = pooled[b * 256 + t];
  __syncthreads();
  int k = blockIdx.x * 256 + t;
  const float4* row = (const float4*)(pjw + (size_t)k * 256);
  double acc[8];
  #pragma unroll
  for (int b = 0; b < 8; b++) acc[b] = 0.0;
  for (int j4 = 0; j4 < 64; j4++) {
    float4 w = row[j4];
    int j = j4 * 4;
    #pragma unroll
    for (int b = 0; b < 8; b++)
      acc[b] += (double)w.x * pl[b][j] + (double)w.y * pl[b][j + 1]
              + (double)w.z * pl[b][j + 2] + (double)w.w * pl[b][j + 3];
  }
  float bias = pjb[k];
  #pragma unroll
  for (int b = 0; b < 8; b++) {
    float ol = (float)(acc[b] + (double)bias);
    oplog[(size_t)b * NOP + k] = ol;
    float key = ol + gop[(size_t)b * NOP + k];
    opkv[(size_t)b * NOP + k] = ((unsigned long long)keymap(key) << 32) | (unsigned)k;
  }
}

static __device__ __forceinline__ float tierf(float h) {
  return h <= 2.f ? 1.f : (h <= 4.f ? 1.5f : (h <= 8.f ? 2.f : (h <= 16.f ? 3.f : 5.f)));
}
static __device__ __forceinline__ double penf(float d) {
  float fwd = d > 0.f ? d : 0.f;
  float bwd = d < 0.f ? -d : 0.f;
  return (double)(fwd * tierf(fwd)) + (double)(bwd * bwd * tierf(bwd));
}

// fused intra (row 1) + inter (row 0) penalties
__global__ void k_pen(const unsigned* __restrict__ perm, const unsigned* __restrict__ oo,
                      double* __restrict__ acc) {
  int g = blockIdx.x * 256 + threadIdx.x;
  int b = g >> 16, k = g & 65535;
  const unsigned* P = perm + (size_t)b * NMEM;
  float A = (float)P[k], Bv = (float)P[NOP + k], Cv = (float)P[2 * NOP + k];
  double pi = penf(Bv - A) + penf(Cv - Bv);
  double pe = 0.0;
  if (k < 65535) {
    unsigned k0 = oo[(size_t)b * NOP + k], k1 = oo[(size_t)b * NOP + k + 1];
    pe = penf((float)P[k1] - (float)P[2 * NOP + k0]);
  }
  __shared__ double ri[256], re[256];
  ri[threadIdx.x] = pi; re[threadIdx.x] = pe;
  __syncthreads();
  for (int off = 128; off > 0; off >>= 1) {
    if (threadIdx.x < off) { ri[threadIdx.x] += ri[threadIdx.x + off]; re[threadIdx.x] += re[threadIdx.x + off]; }
    __syncthreads();
  }
  if (threadIdx.x == 0) { atomicAdd(&acc[8 + b], ri[0]); atomicAdd(&acc[0 + b], re[0]); }
}

__global__ void k_finalize(const double* __restrict__ acc, float* __restrict__ out) {
  if (threadIdx.x < 32) out[threadIdx.x] = (float)acc[threadIdx.x];
}

extern "C" void kernel_launch(void* const* d_in, const int* in_sizes, int n_in,
                              void* d_out, int out_size, void* d_ws, size_t ws_size,
                              hipStream_t stream) {
  (void)in_sizes; (void)n_in; (void)out_size; (void)ws_size;
  const float* ml  = (const float*)d_in[0];
  const float* gm  = (const float*)d_in[1];
  const float* gop = (const float*)d_in[2];
  const float* pmw = (const float*)d_in[3];
  const float* pmb = (const float*)d_in[4];
  const float* mcw = (const float*)d_in[5];
  const float* mcb = (const float*)d_in[6];
  const float* pjw = (const float*)d_in[7];
  const float* pjb = (const float*)d_in[8];
  float* out = (float*)d_out;
  char* ws = (char*)d_ws;

  unsigned long long* kvA = (unsigned long long*)(ws + 0);          // 12,582,912
  unsigned long long* kvB = (unsigned long long*)(ws + 12582912);   // 12,582,912
  unsigned* hist   = (unsigned*)(ws + 25165824);                    //  <= 393,216
  unsigned* perm   = (unsigned*)(ws + 31457280);                    //  6,291,456
  double*   part   = (double*)(ws + 37748736);                      //  3,145,728
  double*   pooled = (double*)(ws + 40894464);
  double*   acc    = (double*)(ws + 40910848);
  float*    segM   = (float*)(ws + 40911104);
  float*    segT   = (float*)(ws + 40923392);
  float*    sufM   = (float*)(ws + 40935680);
  float*    sufT   = (float*)(ws + 40947968);
  // slog reuses the dead kvB region during each PL phase (mem: after sort pass2
  // last reads kvB; op: conv done, opkv* live only in first 8.4MB). Consumed by
  // kpl_main before any later kernel overwrites the region (stream-ordered).
  float*    slog  = (float*)(ws + 12582912);                        // <= 6,291,456
  float* mf = (float*)(ws + 0);                                     // conv phase reuse (25.1 MB)
  unsigned long long* opkvA = (unsigned long long*)(ws + 0);
  unsigned long long* opkvB = (unsigned long long*)(ws + 4194304);
  float*    oplog = (float*)(ws + 8388608);
  unsigned* oo    = (unsigned*)(ws + 10485760);

  k_zero<<<1, 32, 0, stream>>>(acc);

  // ---- mem argsort: pass0 builds keys on the fly; pass3 writes perm directly ----
  k_radix_hist0<<<NB * NC_MEM, 256, 0, stream>>>(ml, gm, hist);
  k_radix_scan<<<NB, 1024, 0, stream>>>(hist, 256 * NC_MEM);
  k_radix_scatter0<<<NB * NC_MEM, 256, 0, stream>>>(ml, gm, kvA, hist);
  k_radix_hist<<<NB * NC_MEM, 256, 0, stream>>>(kvA, hist, NMEM, NC_MEM, 40);
  k_radix_scan<<<NB, 1024, 0, stream>>>(hist, 256 * NC_MEM);
  k_radix_scatter<<<NB * NC_MEM, 256, 0, stream>>>(kvA, kvB, hist, NMEM, NC_MEM, 40);
  k_radix_hist<<<NB * NC_MEM, 256, 0, stream>>>(kvB, hist, NMEM, NC_MEM, 48);
  k_radix_scan<<<NB, 1024, 0, stream>>>(hist, 256 * NC_MEM);
  k_radix_scatter<<<NB * NC_MEM, 256, 0, stream>>>(kvB, kvA, hist, NMEM, NC_MEM, 48);
  k_radix_hist<<<NB * NC_MEM, 256, 0, stream>>>(kvA, hist, NMEM, NC_MEM, 56);
  k_radix_scan<<<NB, 1024, 0, stream>>>(hist, 256 * NC_MEM);
  k_radix_scatter_lo<<<NB * NC_MEM, 256, 0, stream>>>(kvA, perm, hist, NMEM, NC_MEM);

  // mem PL logprob (row 3)
  {
    int nseg = NMEM / LSEG;  // 384
    kpl_seg <<<NB * nseg, 256, 0, stream>>>(ml, perm, NMEM, nseg, segM, segT, slog, acc, 3);
    kpl_scan<<<NB, 512, 0, stream>>>(segM, segT, nseg, sufM, sufT);
    kpl_main<<<NB * nseg, 256, 0, stream>>>(slog, NMEM, nseg, sufM, sufT, acc, 3);
  }

  // ---- conv1 + conv2 + pooling, 2 groups of 4 batches ----
  for (int g = 0; g < 2; g++) {
    k_conv1b<<<4 * NBLK_MEM, 256, 0, stream>>>(perm + (size_t)g * 4 * NMEM, pmw, pmb, mf);
    k_conv2b<<<4 * NBLK_MEM, 256, 0, stream>>>(mf, mcw, mcb, part, g * 4);
  }
  k_pool_final<<<NB, 256, 0, stream>>>(part, pooled);

  // ---- op logits + keys ----
  k_oplogits<<<NOP / 256, 256, 0, stream>>>(pjw, pjb, pooled, gop, oplog, opkvA);

  // ---- op argsort: pass3 writes oo directly ----
  k_radix_hist<<<NB * NC_OP, 256, 0, stream>>>(opkvA, hist, NOP, NC_OP, 32);
  k_radix_scan<<<NB, 1024, 0, stream>>>(hist, 256 * NC_OP);
  k_radix_scatter<<<NB * NC_OP, 256, 0, stream>>>(opkvA, opkvB, hist, NOP, NC_OP, 32);
  k_radix_hist<<<NB * NC_OP, 256, 0, stream>>>(opkvB, hist, NOP, NC_OP, 40);
  k_radix_scan<<<NB, 1024, 0, stream>>>(hist, 256 * NC_OP);
  k_radix_scatter<<<NB * NC_OP, 256, 0, stream>>>(opkvB, opkvA, hist, NOP, NC_OP, 40);
  k_radix_hist<<<NB * NC_OP, 256, 0, stream>>>(opkvA, hist, NOP, NC_OP, 48);
  k_radix_scan<<<NB, 1024, 0, stream>>>(hist, 256 * NC_OP);
  k_radix_scatter<<<NB * NC_OP, 256, 0, stream>>>(opkvA, opkvB, hist, NOP, NC_OP, 48);
  k_radix_hist<<<NB * NC_OP, 256, 0, stream>>>(opkvB, hist, NOP, NC_OP, 56);
  k_radix_scan<<<NB, 1024, 0, stream>>>(hist, 256 * NC_OP);
  k_radix_scatter_lo<<<NB * NC_OP, 256, 0, stream>>>(opkvB, oo, hist, NOP, NC_OP);

  // op PL logprob (row 2)
  {
    int nseg = NOP / LSEG;   // 128
    kpl_seg <<<NB * nseg, 256, 0, stream>>>(oplog, oo, NOP, nseg, segM, segT, slog, acc, 2);
    kpl_scan<<<NB, 512, 0, stream>>>(segM, segT, nseg, sufM, sufT);
    kpl_main<<<NB * nseg, 256, 0, stream>>>(slog, NOP, nseg, sufM, sufT, acc, 2);
  }

  // penalties (rows 0,1)
  k_pen<<<NB * NOP / 256, 256, 0, stream>>>(perm, oo, acc);

  k_finalize<<<1, 32, 0, stream>>>(acc, out);
}

// Round 11
// 498.822 us; speedup vs baseline: 7.8438x; 1.0190x over previous
//
#include <hip/hip_runtime.h>
#include <math.h>

#define NB 8
#define NMEM 196608
#define NOP 65536
#define NBLK_MEM 768
#define LSEG 512
#define EPB 4096
#define NC_MEM 48   // NMEM / EPB
#define NC_OP 16    // NOP / EPB

static __device__ __forceinline__ unsigned keymap(float f) {
  unsigned u = __float_as_uint(f);
  return (u & 0x80000000u) ? ~u : (u | 0x80000000u);
}

// logsumexp state combiner: (M,T) represents M + log(T); T==0 is identity.
static __device__ __forceinline__ void comb(float& M1, float& T1, float M2, float T2) {
  if (T2 == 0.f) return;
  if (T1 == 0.f) { M1 = M2; T1 = T2; return; }
  float M = fmaxf(M1, M2);
  T1 = T1 * expf(M1 - M) + T2 * expf(M2 - M);
  M1 = M;
}

__global__ void k_zero(double* acc) {
  if (threadIdx.x < 32) acc[threadIdx.x] = 0.0;
}

// ---- radix sort: 4x8-bit passes, stable, 4096 elements/block ----
// Batch->XCD pinning: batch = blockIdx.x % 8, so all blocks of one batch land
// on one XCD (round-robin dispatch) and its working set stays in that L2.
__global__ void k_radix_hist0(const float* __restrict__ ml, const float* __restrict__ gm,
                              unsigned* __restrict__ hist) {
  __shared__ unsigned h[256];
  int batch = blockIdx.x % NB, cb = blockIdx.x / NB;
  int t = threadIdx.x;
  h[t] = 0;
  __syncthreads();
  const float* pm = ml + (size_t)batch * NMEM + (size_t)cb * EPB;
  const float* pg = gm + (size_t)batch * NMEM + (size_t)cb * EPB;
  #pragma unroll
  for (int r = 0; r < 16; r++) {
    unsigned key = keymap(pm[r * 256 + t] + pg[r * 256 + t]);
    atomicAdd(&h[key & 255u], 1u);
  }
  __syncthreads();
  hist[((size_t)batch * 256 + t) * NC_MEM + cb] = h[t];
}

__global__ void k_radix_hist(const unsigned long long* __restrict__ src, unsigned* __restrict__ hist,
                             int nper, int nblk, int shift) {
  __shared__ unsigned h[256];
  int batch = blockIdx.x % NB, cb = blockIdx.x / NB;
  int t = threadIdx.x;
  h[t] = 0;
  __syncthreads();
  const unsigned long long* p = src + (size_t)batch * nper + (size_t)cb * EPB;
  #pragma unroll
  for (int r = 0; r < 16; r++) {
    unsigned long long v = p[r * 256 + t];
    unsigned d = (unsigned)(v >> shift) & 255u;
    atomicAdd(&h[d], 1u);
  }
  __syncthreads();
  hist[((size_t)batch * 256 + t) * nblk + cb] = h[t];
}

__global__ void __launch_bounds__(1024) k_radix_scan(unsigned* __restrict__ hist, int L) {
  int b = blockIdx.x, t = threadIdx.x;   // block b -> XCD b%8: hist L2-hot
  unsigned* h = hist + (size_t)b * L;
  int C = L / 1024;
  unsigned s = 0;
  for (int i = 0; i < C; i++) s += h[t * C + i];
  __shared__ unsigned ls[1024];
  ls[t] = s;
  __syncthreads();
  for (int off = 1; off < 1024; off <<= 1) {
    unsigned add = (t >= off) ? ls[t - off] : 0u;
    __syncthreads();
    ls[t] += add;
    __syncthreads();
  }
  unsigned run = (t > 0) ? ls[t - 1] : 0u;
  for (int i = 0; i < C; i++) { unsigned v = h[t * C + i]; h[t * C + i] = run; run += v; }
}

// stable in-block rank: pos = base[d] + run[d] + wave-exclusive + ballot lane rank.
#define SCATTER_BODY(GETV, WRITE)                                              \
  __shared__ unsigned base[256];                                               \
  __shared__ unsigned run[256];                                                \
  __shared__ unsigned wh[4][256];                                              \
  int t = threadIdx.x, lane = t & 63, wv = t >> 6;                             \
  base[t] = hist[((size_t)batch * 256 + t) * nblk + cb];                       \
  run[t] = 0;                                                                  \
  unsigned long long v[16];                                                    \
  GETV;                                                                        \
  __syncthreads();                                                             \
  _Pragma("unroll")                                                            \
  for (int r = 0; r < 16; r++) {                                               \
    unsigned d = (unsigned)(v[r] >> shift) & 255u;                             \
    unsigned long long m = ~0ull;                                              \
    _Pragma("unroll")                                                          \
    for (int bit = 0; bit < 8; bit++) {                                        \
      unsigned long long bal = __ballot((d >> bit) & 1u);                      \
      m &= ((d >> bit) & 1u) ? bal : ~bal;                                     \
    }                                                                          \
    unsigned rank = (unsigned)__popcll(m & ((1ull << lane) - 1ull));           \
    _Pragma("unroll")                                                          \
    for (int w = 0; w < 4; w++) wh[w][t] = 0;                                  \
    __syncthreads();                                                           \
    if (rank == 0) wh[wv][d] = (unsigned)__popcll(m);                          \
    __syncthreads();                                                           \
    {                                                                          \
      unsigned run_t = run[t];                                                 \
      _Pragma("unroll")                                                        \
      for (int w = 0; w < 4; w++) { unsigned x = wh[w][t]; wh[w][t] = run_t; run_t += x; } \
      run[t] = run_t;                                                          \
    }                                                                          \
    __syncthreads();                                                           \
    unsigned pos = base[d] + wh[wv][d] + rank;                                 \
    WRITE;                                                                     \
    __syncthreads();                                                           \
  }

__global__ void k_radix_scatter0(const float* __restrict__ ml, const float* __restrict__ gm,
                                 unsigned long long* __restrict__ dst, const unsigned* __restrict__ hist) {
  int batch = blockIdx.x % NB, cb = blockIdx.x / NB;
  const int nblk = NC_MEM, shift = 32;
  const float* pm = ml + (size_t)batch * NMEM + (size_t)cb * EPB;
  const float* pg = gm + (size_t)batch * NMEM + (size_t)cb * EPB;
  unsigned long long* q = dst + (size_t)batch * NMEM;
  SCATTER_BODY(
    { _Pragma("unroll")
      for (int r = 0; r < 16; r++) {
        unsigned key = keymap(pm[r * 256 + t] + pg[r * 256 + t]);
        v[r] = ((unsigned long long)key << 32) | (unsigned)(cb * EPB + r * 256 + t);
      } },
    { q[pos] = v[r]; })
}

__global__ void k_radix_scatter(const unsigned long long* __restrict__ src, unsigned long long* __restrict__ dst,
                                const unsigned* __restrict__ hist, int nper, int nblk, int shift) {
  int batch = blockIdx.x % NB, cb = blockIdx.x / NB;
  const unsigned long long* p = src + (size_t)batch * nper + (size_t)cb * EPB;
  unsigned long long* q = dst + (size_t)batch * nper;
  SCATTER_BODY(
    { _Pragma("unroll")
      for (int r = 0; r < 16; r++) v[r] = p[r * 256 + t]; },
    { q[pos] = v[r]; })
}

// last pass: write only the low 32 bits (the permutation index).
__global__ void k_radix_scatter_lo(const unsigned long long* __restrict__ src, unsigned* __restrict__ dst,
                                   const unsigned* __restrict__ hist, int nper, int nblk) {
  int batch = blockIdx.x % NB, cb = blockIdx.x / NB;
  const int shift = 56;
  const unsigned long long* p = src + (size_t)batch * nper + (size_t)cb * EPB;
  unsigned* q = dst + (size_t)batch * nper;
  SCATTER_BODY(
    { _Pragma("unroll")
      for (int r = 0; r < 16; r++) v[r] = p[r * 256 + t]; },
    { q[pos] = (unsigned)v[r]; })
}

// ---- Plackett-Luce: segmented reverse-cumlogsumexp ----
// Pass 1 gathers logits[order] ONCE (batch pinned to one XCD -> L2-hit gathers)
// and stores them contiguous (slog) for pass 3.
__global__ void kpl_seg(const float* __restrict__ logits, const unsigned* __restrict__ order,
                        int n, int nseg, float* __restrict__ segM, float* __restrict__ segT,
                        float* __restrict__ slog, double* __restrict__ acc, int row) {
  int bs = blockIdx.x;
  int b = bs % NB, seg = bs / NB;
  int t = threadIdx.x;
  const float* lg = logits + (size_t)b * n;
  const unsigned* od = order + (size_t)b * n + (size_t)seg * LSEG;
  float s0 = lg[od[t * 2]], s1 = lg[od[t * 2 + 1]];
  *((float2*)&slog[(size_t)b * n + (size_t)seg * LSEG + t * 2]) = make_float2(s0, s1);
  float m = fmaxf(s0, s1);
  float T = expf(s0 - m) + expf(s1 - m);
  double ss = (double)s0 + (double)s1;
  __shared__ float sm[256], st_[256];
  __shared__ double sd[256];
  sm[t] = m; st_[t] = T; sd[t] = ss;
  __syncthreads();
  for (int off = 128; off > 0; off >>= 1) {
    if (t < off) { comb(sm[t], st_[t], sm[t + off], st_[t + off]); sd[t] += sd[t + off]; }
    __syncthreads();
  }
  if (t == 0) { segM[b * nseg + seg] = sm[0]; segT[b * nseg + seg] = st_[0]; atomicAdd(&acc[row * 8 + b], sd[0]); }
}

__global__ void __launch_bounds__(512) kpl_scan(const float* __restrict__ segM, const float* __restrict__ segT,
                                                int nseg, float* __restrict__ sufM, float* __restrict__ sufT) {
  int b = blockIdx.x, t = threadIdx.x;
  __shared__ float sm[512], st_[512];
  float M = -INFINITY, T = 0.f;
  if (t < nseg) { M = segM[b * nseg + t]; T = segT[b * nseg + t]; }
  sm[t] = M; st_[t] = T;
  __syncthreads();
  for (int off = 1; off < 512; off <<= 1) {
    float M2 = -INFINITY, T2 = 0.f;
    if (t + off < 512) { M2 = sm[t + off]; T2 = st_[t + off]; }
    __syncthreads();
    comb(M, T, M2, T2);
    sm[t] = M; st_[t] = T;
    __syncthreads();
  }
  if (t < nseg) {
    float eM = -INFINITY, eT = 0.f;
    if (t + 1 < nseg) { eM = sm[t + 1]; eT = st_[t + 1]; }
    sufM[b * nseg + t] = eM; sufT[b * nseg + t] = eT;
  }
}

// Pass 3 reads slog coalesced (no re-gather); same batch->XCD pinning.
__global__ void kpl_main(const float* __restrict__ slog, int n, int nseg,
                         const float* __restrict__ sufM, const float* __restrict__ sufT,
                         double* __restrict__ acc, int row) {
  int bs = blockIdx.x;
  int b = bs % NB, seg = bs / NB;
  int t = threadIdx.x;
  float2 s01 = *((const float2*)&slog[(size_t)b * n + (size_t)seg * LSEG + t * 2]);
  float s0 = s01.x, s1 = s01.y;
  float m = fmaxf(s0, s1);
  float T = expf(s0 - m) + expf(s1 - m);
  __shared__ float sm[256], st_[256];
  sm[t] = m; st_[t] = T;
  __syncthreads();
  float Mi = m, Ti = T;
  for (int off = 1; off < 256; off <<= 1) {
    float M2 = -INFINITY, T2 = 0.f;
    if (t + off < 256) { M2 = sm[t + off]; T2 = st_[t + off]; }
    __syncthreads();
    comb(Mi, Ti, M2, T2);
    sm[t] = Mi; st_[t] = Ti;
    __syncthreads();
  }
  float Mx = -INFINITY, Tx = 0.f;
  if (t + 1 < 256) { Mx = sm[t + 1]; Tx = st_[t + 1]; }
  comb(Mx, Tx, sufM[b * nseg + seg], sufT[b * nseg + seg]);
  double lsum = 0.0;
  {
    float s = s1;
    if (Tx == 0.f) { Mx = s; Tx = 1.f; }
    else if (s > Mx) { Tx = Tx * expf(Mx - s) + 1.f; Mx = s; }
    else Tx += expf(s - Mx);
    lsum += (double)Mx + (double)logf(Tx);
    s = s0;
    if (s > Mx) { Tx = Tx * expf(Mx - s) + 1.f; Mx = s; }
    else Tx += expf(s - Mx);
    lsum += (double)Mx + (double)logf(Tx);
  }
  __shared__ double sd[256];
  sd[t] = lsum;
  __syncthreads();
  for (int off = 128; off > 0; off >>= 1) { if (t < off) sd[t] += sd[t + off]; __syncthreads(); }
  if (t == 0) atomicAdd(&acc[row * 8 + b], -sd[0]);
}

// conv1 batched over 4 batches; mm is block-uniform (derived from blockIdx only)
// so weight/bias reads are scalar (s_load via constant cache), not LDS/VALU.
__global__ void k_conv1b(const unsigned* __restrict__ permg, const float* __restrict__ pmw,
                         const float* __restrict__ pmb, float* __restrict__ mf) {
  int t = threadIdx.x;
  int b4 = blockIdx.x / NBLK_MEM;
  int g0 = (blockIdx.x % NBLK_MEM) * 256;     // block-uniform
  int mm = g0 >> 16;                          // uniform: blocks never straddle 65536
  int p = (g0 & 65535) + t;
  int i = p >> 8, j = p & 255;
  const unsigned* ad = permg + (size_t)b4 * NMEM + mm * 65536;
  float nb[3][3];
  #pragma unroll
  for (int di = 0; di < 3; di++)
    #pragma unroll
    for (int dj = 0; dj < 3; dj++) {
      int ii = i + di - 1, jj = j + dj - 1;
      nb[di][dj] = (ii >= 0 && ii < 256 && jj >= 0 && jj < 256) ? (float)ad[ii * 256 + jj] : 0.f;
    }
  unsigned c = ad[p];
  float o[8];
  #pragma unroll
  for (int oc = 0; oc < 8; oc++) {
    float s = pmb[mm * 8 + oc];
    #pragma unroll
    for (int di = 0; di < 3; di++)
      #pragma unroll
      for (int dj = 0; dj < 3; dj++)
        s += pmw[mm * 72 + oc * 9 + di * 3 + dj] * nb[di][dj];
    o[oc] = fmaxf(s, 0.f);
  }
  float4* dst = (float4*)(mf + ((size_t)b4 * NMEM + c) * 8);
  dst[0] = make_float4(o[0], o[1], o[2], o[3]);
  dst[1] = make_float4(o[4], o[5], o[6], o[7]);
}

// conv2 (R3 structure, global nb loads = cache hits), weights/bias read directly
// from global with compile-time-constant indices -> scalar loads.
__global__ void k_conv2b(const float* __restrict__ mf, const float* __restrict__ mcw,
                         const float* __restrict__ mcb, double* __restrict__ part, int gb) {
  __shared__ float pw[4][16][4];
  int t = threadIdx.x;
  int b4 = blockIdx.x / NBLK_MEM;
  int blk = blockIdx.x % NBLK_MEM;
  int r = blk * 32 + (t >> 3);
  int l = t & 7;
  const float* base = mf + (size_t)b4 * (NMEM * 8);
  float nb[9][8];
  #pragma unroll
  for (int q = 0; q < 9; q++) {
    int rr = r + q / 3 - 1, ll = l + q % 3 - 1;
    if (rr >= 0 && rr < 24576 && ll >= 0 && ll < 8) {
      const float4* px = (const float4*)(base + ((size_t)rr * 8 + ll) * 8);
      float4 a = px[0], bb = px[1];
      nb[q][0] = a.x; nb[q][1] = a.y; nb[q][2] = a.z; nb[q][3] = a.w;
      nb[q][4] = bb.x; nb[q][5] = bb.y; nb[q][6] = bb.z; nb[q][7] = bb.w;
    } else {
      #pragma unroll
      for (int c = 0; c < 8; c++) nb[q][c] = 0.f;
    }
  }
  int lane = t & 63, wv = t >> 6;
  #pragma unroll
  for (int c2 = 0; c2 < 16; c2++) {
    float s = mcb[c2];
    #pragma unroll
    for (int c = 0; c < 8; c++)
      #pragma unroll
      for (int q = 0; q < 9; q++)
        s += mcw[c2 * 72 + c * 9 + q] * nb[q][c];
    float v = fmaxf(s, 0.f);
    v += __shfl_xor(v, 1);
    v += __shfl_xor(v, 8);
    v += __shfl_xor(v, 16);
    v += __shfl_xor(v, 32);
    if ((lane & 1) == 0 && ((t >> 3) & 7) == 0) pw[wv][c2][(lane & 7) >> 1] = v;
  }
  __syncthreads();
  if (t < 64) {
    int c2 = t >> 2, d = t & 3;
    double s = (double)pw[0][c2][d] + (double)pw[1][c2][d] + (double)pw[2][c2][d] + (double)pw[3][c2][d];
    part[((size_t)(gb + b4) * NBLK_MEM + blk) * 64 + t] = s;
  }
}

__global__ void k_pool_final(const double* __restrict__ part, double* __restrict__ pooled) {
  int b = blockIdx.x, t = threadIdx.x;       // t = c2*16 + a*4 + d
  int c2 = t >> 4, a = (t >> 2) & 3, d = t & 3;
  double s = 0.0;
  for (int j = 0; j < 192; j++)
    s += part[((size_t)b * NBLK_MEM + a * 192 + j) * 64 + c2 * 4 + d];
  pooled[b * 256 + t] = s / 12288.0;
}

__global__ void k_oplogits(const float* __restrict__ pjw, const float* __restrict__ pjb,
                           const double* __restrict__ pooled, const float* __restrict__ gop,
                           float* __restrict__ oplog, unsigned long long* __restrict__ opkv) {
  __shared__ double pl[8][256];
  int t = threadIdx.x;
  #pragma unroll
  for (int b = 0; b < 8; b++) pl[b][t] = pooled[b * 256 + t];
  __syncthreads();
  int k = blockIdx.x * 256 + t;
  const float4* row = (const float4*)(pjw + (size_t)k * 256);
  double acc[8];
  #pragma unroll
  for (int b = 0; b < 8; b++) acc[b] = 0.0;
  for (int j4 = 0; j4 < 64; j4++) {
    float4 w = row[j4];
    int j = j4 * 4;
    #pragma unroll
    for (int b = 0; b < 8; b++)
      acc[b] += (double)w.x * pl[b][j] + (double)w.y * pl[b][j + 1]
              + (double)w.z * pl[b][j + 2] + (double)w.w * pl[b][j + 3];
  }
  float bias = pjb[k];
  #pragma unroll
  for (int b = 0; b < 8; b++) {
    float ol = (float)(acc[b] + (double)bias);
    oplog[(size_t)b * NOP + k] = ol;
    float key = ol + gop[(size_t)b * NOP + k];
    opkv[(size_t)b * NOP + k] = ((unsigned long long)keymap(key) << 32) | (unsigned)k;
  }
}

static __device__ __forceinline__ float tierf(float h) {
  return h <= 2.f ? 1.f : (h <= 4.f ? 1.5f : (h <= 8.f ? 2.f : (h <= 16.f ? 3.f : 5.f)));
}
static __device__ __forceinline__ double penf(float d) {
  float fwd = d > 0.f ? d : 0.f;
  float bwd = d < 0.f ? -d : 0.f;
  return (double)(fwd * tierf(fwd)) + (double)(bwd * bwd * tierf(bwd));
}

// fused intra (row 1) + inter (row 0) penalties; batch->XCD pinned
__global__ void k_pen(const unsigned* __restrict__ perm, const unsigned* __restrict__ oo,
                      double* __restrict__ acc) {
  int b = blockIdx.x % NB;
  int k = (blockIdx.x / NB) * 256 + threadIdx.x;
  const unsigned* P = perm + (size_t)b * NMEM;
  float A = (float)P[k], Bv = (float)P[NOP + k], Cv = (float)P[2 * NOP + k];
  double pi = penf(Bv - A) + penf(Cv - Bv);
  double pe = 0.0;
  if (k < 65535) {
    unsigned k0 = oo[(size_t)b * NOP + k], k1 = oo[(size_t)b * NOP + k + 1];
    pe = penf((float)P[k1] - (float)P[2 * NOP + k0]);
  }
  __shared__ double ri[256], re[256];
  ri[threadIdx.x] = pi; re[threadIdx.x] = pe;
  __syncthreads();
  for (int off = 128; off > 0; off >>= 1) {
    if (threadIdx.x < off) { ri[threadIdx.x] += ri[threadIdx.x + off]; re[threadIdx.x] += re[threadIdx.x + off]; }
    __syncthreads();
  }
  if (threadIdx.x == 0) { atomicAdd(&acc[8 + b], ri[0]); atomicAdd(&acc[0 + b], re[0]); }
}

__global__ void k_finalize(const double* __restrict__ acc, float* __restrict__ out) {
  if (threadIdx.x < 32) out[threadIdx.x] = (float)acc[threadIdx.x];
}

extern "C" void kernel_launch(void* const* d_in, const int* in_sizes, int n_in,
                              void* d_out, int out_size, void* d_ws, size_t ws_size,
                              hipStream_t stream) {
  (void)in_sizes; (void)n_in; (void)out_size; (void)ws_size;
  const float* ml  = (const float*)d_in[0];
  const float* gm  = (const float*)d_in[1];
  const float* gop = (const float*)d_in[2];
  const float* pmw = (const float*)d_in[3];
  const float* pmb = (const float*)d_in[4];
  const float* mcw = (const float*)d_in[5];
  const float* mcb = (const float*)d_in[6];
  const float* pjw = (const float*)d_in[7];
  const float* pjb = (const float*)d_in[8];
  float* out = (float*)d_out;
  char* ws = (char*)d_ws;

  unsigned long long* kvA = (unsigned long long*)(ws + 0);          // 12,582,912
  unsigned long long* kvB = (unsigned long long*)(ws + 12582912);   // 12,582,912
  unsigned* hist   = (unsigned*)(ws + 25165824);                    //  <= 393,216
  unsigned* perm   = (unsigned*)(ws + 31457280);                    //  6,291,456
  double*   part   = (double*)(ws + 37748736);                      //  3,145,728
  double*   pooled = (double*)(ws + 40894464);
  double*   acc    = (double*)(ws + 40910848);
  float*    segM   = (float*)(ws + 40911104);
  float*    segT   = (float*)(ws + 40923392);
  float*    sufM   = (float*)(ws + 40935680);
  float*    sufT   = (float*)(ws + 40947968);
  float*    slog  = (float*)(ws + 12582912);                        // reuses dead kvB
  float* mf = (float*)(ws + 0);                                     // conv phase reuse (25.1 MB)
  unsigned long long* opkvA = (unsigned long long*)(ws + 0);
  unsigned long long* opkvB = (unsigned long long*)(ws + 4194304);
  float*    oplog = (float*)(ws + 8388608);
  unsigned* oo    = (unsigned*)(ws + 10485760);

  k_zero<<<1, 32, 0, stream>>>(acc);

  // ---- mem argsort: pass0 builds keys on the fly; pass3 writes perm directly ----
  k_radix_hist0<<<NB * NC_MEM, 256, 0, stream>>>(ml, gm, hist);
  k_radix_scan<<<NB, 1024, 0, stream>>>(hist, 256 * NC_MEM);
  k_radix_scatter0<<<NB * NC_MEM, 256, 0, stream>>>(ml, gm, kvA, hist);
  k_radix_hist<<<NB * NC_MEM, 256, 0, stream>>>(kvA, hist, NMEM, NC_MEM, 40);
  k_radix_scan<<<NB, 1024, 0, stream>>>(hist, 256 * NC_MEM);
  k_radix_scatter<<<NB * NC_MEM, 256, 0, stream>>>(kvA, kvB, hist, NMEM, NC_MEM, 40);
  k_radix_hist<<<NB * NC_MEM, 256, 0, stream>>>(kvB, hist, NMEM, NC_MEM, 48);
  k_radix_scan<<<NB, 1024, 0, stream>>>(hist, 256 * NC_MEM);
  k_radix_scatter<<<NB * NC_MEM, 256, 0, stream>>>(kvB, kvA, hist, NMEM, NC_MEM, 48);
  k_radix_hist<<<NB * NC_MEM, 256, 0, stream>>>(kvA, hist, NMEM, NC_MEM, 56);
  k_radix_scan<<<NB, 1024, 0, stream>>>(hist, 256 * NC_MEM);
  k_radix_scatter_lo<<<NB * NC_MEM, 256, 0, stream>>>(kvA, perm, hist, NMEM, NC_MEM);

  // mem PL logprob (row 3)
  {
    int nseg = NMEM / LSEG;  // 384
    kpl_seg <<<NB * nseg, 256, 0, stream>>>(ml, perm, NMEM, nseg, segM, segT, slog, acc, 3);
    kpl_scan<<<NB, 512, 0, stream>>>(segM, segT, nseg, sufM, sufT);
    kpl_main<<<NB * nseg, 256, 0, stream>>>(slog, NMEM, nseg, sufM, sufT, acc, 3);
  }

  // ---- conv1 + conv2 + pooling, 2 groups of 4 batches ----
  for (int g = 0; g < 2; g++) {
    k_conv1b<<<4 * NBLK_MEM, 256, 0, stream>>>(perm + (size_t)g * 4 * NMEM, pmw, pmb, mf);
    k_conv2b<<<4 * NBLK_MEM, 256, 0, stream>>>(mf, mcw, mcb, part, g * 4);
  }
  k_pool_final<<<NB, 256, 0, stream>>>(part, pooled);

  // ---- op logits + keys ----
  k_oplogits<<<NOP / 256, 256, 0, stream>>>(pjw, pjb, pooled, gop, oplog, opkvA);

  // ---- op argsort: pass3 writes oo directly ----
  k_radix_hist<<<NB * NC_OP, 256, 0, stream>>>(opkvA, hist, NOP, NC_OP, 32);
  k_radix_scan<<<NB, 1024, 0, stream>>>(hist, 256 * NC_OP);
  k_radix_scatter<<<NB * NC_OP, 256, 0, stream>>>(opkvA, opkvB, hist, NOP, NC_OP, 32);
  k_radix_hist<<<NB * NC_OP, 256, 0, stream>>>(opkvB, hist, NOP, NC_OP, 40);
  k_radix_scan<<<NB, 1024, 0, stream>>>(hist, 256 * NC_OP);
  k_radix_scatter<<<NB * NC_OP, 256, 0, stream>>>(opkvB, opkvA, hist, NOP, NC_OP, 40);
  k_radix_hist<<<NB * NC_OP, 256, 0, stream>>>(opkvA, hist, NOP, NC_OP, 48);
  k_radix_scan<<<NB, 1024, 0, stream>>>(hist, 256 * NC_OP);
  k_radix_scatter<<<NB * NC_OP, 256, 0, stream>>>(opkvA, opkvB, hist, NOP, NC_OP, 48);
  k_radix_hist<<<NB * NC_OP, 256, 0, stream>>>(opkvB, hist, NOP, NC_OP, 56);
  k_radix_scan<<<NB, 1024, 0, stream>>>(hist, 256 * NC_OP);
  k_radix_scatter_lo<<<NB * NC_OP, 256, 0, stream>>>(opkvB, oo, hist, NOP, NC_OP);

  // op PL logprob (row 2)
  {
    int nseg = NOP / LSEG;   // 128
    kpl_seg <<<NB * nseg, 256, 0, stream>>>(oplog, oo, NOP, nseg, segM, segT, slog, acc, 2);
    kpl_scan<<<NB, 512, 0, stream>>>(segM, segT, nseg, sufM, sufT);
    kpl_main<<<NB * nseg, 256, 0, stream>>>(slog, NOP, nseg, sufM, sufT, acc, 2);
  }

  // penalties (rows 0,1)
  k_pen<<<NB * NOP / 256, 256, 0, stream>>>(perm, oo, acc);

  k_finalize<<<1, 32, 0, stream>>>(acc, out);
}

// Round 12
// 462.746 us; speedup vs baseline: 8.4553x; 1.0780x over previous
//
#include <hip/hip_runtime.h>
#include <math.h>

#define NB 8
#define NMEM 196608
#define NOP 65536
#define NBLK_MEM 768
#define LSEG 512
#define EPB 4096
#define NC_MEM 48   // NMEM / EPB
#define NC_OP 16    // NOP / EPB

static __device__ __forceinline__ unsigned keymap(float f) {
  unsigned u = __float_as_uint(f);
  return (u & 0x80000000u) ? ~u : (u | 0x80000000u);
}

// logsumexp state combiner: (M,T) represents M + log(T); T==0 is identity.
static __device__ __forceinline__ void comb(float& M1, float& T1, float M2, float T2) {
  if (T2 == 0.f) return;
  if (T1 == 0.f) { M1 = M2; T1 = T2; return; }
  float M = fmaxf(M1, M2);
  T1 = T1 * expf(M1 - M) + T2 * expf(M2 - M);
  M1 = M;
}

__global__ void k_zero(double* acc) {
  if (threadIdx.x < 32) acc[threadIdx.x] = 0.0;
}

// ---- radix sort: 4x8-bit passes, stable, 4096 elements/block ----
// Batch->XCD pinning: batch = blockIdx.x % 8, so all blocks of one batch land
// on one XCD (round-robin dispatch) and its working set stays in that L2.
__global__ void k_radix_hist0(const float* __restrict__ ml, const float* __restrict__ gm,
                              unsigned* __restrict__ hist) {
  __shared__ unsigned h[256];
  int batch = blockIdx.x % NB, cb = blockIdx.x / NB;
  int t = threadIdx.x;
  h[t] = 0;
  __syncthreads();
  const float* pm = ml + (size_t)batch * NMEM + (size_t)cb * EPB;
  const float* pg = gm + (size_t)batch * NMEM + (size_t)cb * EPB;
  #pragma unroll
  for (int r = 0; r < 16; r++) {
    unsigned key = keymap(pm[r * 256 + t] + pg[r * 256 + t]);
    atomicAdd(&h[key & 255u], 1u);
  }
  __syncthreads();
  hist[((size_t)batch * 256 + t) * NC_MEM + cb] = h[t];
}

__global__ void k_radix_hist(const unsigned long long* __restrict__ src, unsigned* __restrict__ hist,
                             int nper, int nblk, int shift) {
  __shared__ unsigned h[256];
  int batch = blockIdx.x % NB, cb = blockIdx.x / NB;
  int t = threadIdx.x;
  h[t] = 0;
  __syncthreads();
  const unsigned long long* p = src + (size_t)batch * nper + (size_t)cb * EPB;
  #pragma unroll
  for (int r = 0; r < 16; r++) {
    unsigned long long v = p[r * 256 + t];
    unsigned d = (unsigned)(v >> shift) & 255u;
    atomicAdd(&h[d], 1u);
  }
  __syncthreads();
  hist[((size_t)batch * 256 + t) * nblk + cb] = h[t];
}

__global__ void __launch_bounds__(1024) k_radix_scan(unsigned* __restrict__ hist, int L) {
  int b = blockIdx.x, t = threadIdx.x;   // block b -> XCD b%8: hist L2-hot
  unsigned* h = hist + (size_t)b * L;
  int C = L / 1024;
  unsigned s = 0;
  for (int i = 0; i < C; i++) s += h[t * C + i];
  __shared__ unsigned ls[1024];
  ls[t] = s;
  __syncthreads();
  for (int off = 1; off < 1024; off <<= 1) {
    unsigned add = (t >= off) ? ls[t - off] : 0u;
    __syncthreads();
    ls[t] += add;
    __syncthreads();
  }
  unsigned run = (t > 0) ? ls[t - 1] : 0u;
  for (int i = 0; i < C; i++) { unsigned v = h[t * C + i]; h[t * C + i] = run; run += v; }
}

// stable in-block rank: pos = base[d] + run[d] + wave-exclusive + ballot lane rank.
#define SCATTER_BODY(GETV, WRITE)                                              \
  __shared__ unsigned base[256];                                               \
  __shared__ unsigned run[256];                                                \
  __shared__ unsigned wh[4][256];                                              \
  int t = threadIdx.x, lane = t & 63, wv = t >> 6;                             \
  base[t] = hist[((size_t)batch * 256 + t) * nblk + cb];                       \
  run[t] = 0;                                                                  \
  unsigned long long v[16];                                                    \
  GETV;                                                                        \
  __syncthreads();                                                             \
  _Pragma("unroll")                                                            \
  for (int r = 0; r < 16; r++) {                                               \
    unsigned d = (unsigned)(v[r] >> shift) & 255u;                             \
    unsigned long long m = ~0ull;                                              \
    _Pragma("unroll")                                                          \
    for (int bit = 0; bit < 8; bit++) {                                        \
      unsigned long long bal = __ballot((d >> bit) & 1u);                      \
      m &= ((d >> bit) & 1u) ? bal : ~bal;                                     \
    }                                                                          \
    unsigned rank = (unsigned)__popcll(m & ((1ull << lane) - 1ull));           \
    _Pragma("unroll")                                                          \
    for (int w = 0; w < 4; w++) wh[w][t] = 0;                                  \
    __syncthreads();                                                           \
    if (rank == 0) wh[wv][d] = (unsigned)__popcll(m);                          \
    __syncthreads();                                                           \
    {                                                                          \
      unsigned run_t = run[t];                                                 \
      _Pragma("unroll")                                                        \
      for (int w = 0; w < 4; w++) { unsigned x = wh[w][t]; wh[w][t] = run_t; run_t += x; } \
      run[t] = run_t;                                                          \
    }                                                                          \
    __syncthreads();                                                           \
    unsigned pos = base[d] + wh[wv][d] + rank;                                 \
    WRITE;                                                                     \
    __syncthreads();                                                           \
  }

__global__ void k_radix_scatter0(const float* __restrict__ ml, const float* __restrict__ gm,
                                 unsigned long long* __restrict__ dst, const unsigned* __restrict__ hist) {
  int batch = blockIdx.x % NB, cb = blockIdx.x / NB;
  const int nblk = NC_MEM, shift = 32;
  const float* pm = ml + (size_t)batch * NMEM + (size_t)cb * EPB;
  const float* pg = gm + (size_t)batch * NMEM + (size_t)cb * EPB;
  unsigned long long* q = dst + (size_t)batch * NMEM;
  SCATTER_BODY(
    { _Pragma("unroll")
      for (int r = 0; r < 16; r++) {
        unsigned key = keymap(pm[r * 256 + t] + pg[r * 256 + t]);
        v[r] = ((unsigned long long)key << 32) | (unsigned)(cb * EPB + r * 256 + t);
      } },
    { q[pos] = v[r]; })
}

__global__ void k_radix_scatter(const unsigned long long* __restrict__ src, unsigned long long* __restrict__ dst,
                                const unsigned* __restrict__ hist, int nper, int nblk, int shift) {
  int batch = blockIdx.x % NB, cb = blockIdx.x / NB;
  const unsigned long long* p = src + (size_t)batch * nper + (size_t)cb * EPB;
  unsigned long long* q = dst + (size_t)batch * nper;
  SCATTER_BODY(
    { _Pragma("unroll")
      for (int r = 0; r < 16; r++) v[r] = p[r * 256 + t]; },
    { q[pos] = v[r]; })
}

// last pass: write only the low 32 bits (the permutation index).
__global__ void k_radix_scatter_lo(const unsigned long long* __restrict__ src, unsigned* __restrict__ dst,
                                   const unsigned* __restrict__ hist, int nper, int nblk) {
  int batch = blockIdx.x % NB, cb = blockIdx.x / NB;
  const int shift = 56;
  const unsigned long long* p = src + (size_t)batch * nper + (size_t)cb * EPB;
  unsigned* q = dst + (size_t)batch * nper;
  SCATTER_BODY(
    { _Pragma("unroll")
      for (int r = 0; r < 16; r++) v[r] = p[r * 256 + t]; },
    { q[pos] = (unsigned)v[r]; })
}

// ---- Plackett-Luce: segmented reverse-cumlogsumexp ----
// Pass 1: one WAVE per segment (4 segments/block); each lane gathers 8 elements
// (high ILP), stores them contiguous to slog; 6-round shuffle butterfly reduce
// (no barriers). One f64 atomic per block.
__global__ void kpl_seg(const float* __restrict__ logits, const unsigned* __restrict__ order,
                        int n, int nseg, float* __restrict__ segM, float* __restrict__ segT,
                        float* __restrict__ slog, double* __restrict__ acc, int row) {
  int b = blockIdx.x % NB;
  int sg = blockIdx.x / NB;
  int t = threadIdx.x, lane = t & 63, wv = t >> 6;
  int seg = sg * 4 + wv;
  const float* lg = logits + (size_t)b * n;
  const unsigned* od = order + (size_t)b * n + (size_t)seg * LSEG + lane * 8;
  uint4 i0 = *((const uint4*)od);
  uint4 i1 = *((const uint4*)(od + 4));
  float s0 = lg[i0.x], s1 = lg[i0.y], s2 = lg[i0.z], s3 = lg[i0.w];
  float s4 = lg[i1.x], s5 = lg[i1.y], s6 = lg[i1.z], s7 = lg[i1.w];
  float* sl = slog + (size_t)b * n + (size_t)seg * LSEG + lane * 8;
  *((float4*)sl) = make_float4(s0, s1, s2, s3);
  *((float4*)(sl + 4)) = make_float4(s4, s5, s6, s7);
  float m = fmaxf(fmaxf(fmaxf(s0, s1), fmaxf(s2, s3)),
                  fmaxf(fmaxf(s4, s5), fmaxf(s6, s7)));
  float T = expf(s0 - m) + expf(s1 - m) + expf(s2 - m) + expf(s3 - m)
          + expf(s4 - m) + expf(s5 - m) + expf(s6 - m) + expf(s7 - m);
  double ss = ((double)s0 + (double)s1) + ((double)s2 + (double)s3)
            + ((double)s4 + (double)s5) + ((double)s6 + (double)s7);
  #pragma unroll
  for (int off = 1; off < 64; off <<= 1) {
    float M2 = __shfl_xor(m, off);
    float T2 = __shfl_xor(T, off);
    comb(m, T, M2, T2);
    ss += __shfl_xor(ss, off);
  }
  __shared__ double sw[4];
  if (lane == 0) { segM[b * nseg + seg] = m; segT[b * nseg + seg] = T; sw[wv] = ss; }
  __syncthreads();
  if (t == 0) atomicAdd(&acc[row * 8 + b], (sw[0] + sw[1]) + (sw[2] + sw[3]));
}

__global__ void __launch_bounds__(512) kpl_scan(const float* __restrict__ segM, const float* __restrict__ segT,
                                                int nseg, float* __restrict__ sufM, float* __restrict__ sufT) {
  int b = blockIdx.x, t = threadIdx.x;
  __shared__ float sm[512], st_[512];
  float M = -INFINITY, T = 0.f;
  if (t < nseg) { M = segM[b * nseg + t]; T = segT[b * nseg + t]; }
  sm[t] = M; st_[t] = T;
  __syncthreads();
  for (int off = 1; off < 512; off <<= 1) {
    float M2 = -INFINITY, T2 = 0.f;
    if (t + off < 512) { M2 = sm[t + off]; T2 = st_[t + off]; }
    __syncthreads();
    comb(M, T, M2, T2);
    sm[t] = M; st_[t] = T;
    __syncthreads();
  }
  if (t < nseg) {
    float eM = -INFINITY, eT = 0.f;
    if (t + 1 < nseg) { eM = sm[t + 1]; eT = st_[t + 1]; }
    sufM[b * nseg + t] = eM; sufT[b * nseg + t] = eT;
  }
}

// Pass 3 reads slog coalesced (no re-gather); same batch->XCD pinning.
__global__ void kpl_main(const float* __restrict__ slog, int n, int nseg,
                         const float* __restrict__ sufM, const float* __restrict__ sufT,
                         double* __restrict__ acc, int row) {
  int bs = blockIdx.x;
  int b = bs % NB, seg = bs / NB;
  int t = threadIdx.x;
  float2 s01 = *((const float2*)&slog[(size_t)b * n + (size_t)seg * LSEG + t * 2]);
  float s0 = s01.x, s1 = s01.y;
  float m = fmaxf(s0, s1);
  float T = expf(s0 - m) + expf(s1 - m);
  __shared__ float sm[256], st_[256];
  sm[t] = m; st_[t] = T;
  __syncthreads();
  float Mi = m, Ti = T;
  for (int off = 1; off < 256; off <<= 1) {
    float M2 = -INFINITY, T2 = 0.f;
    if (t + off < 256) { M2 = sm[t + off]; T2 = st_[t + off]; }
    __syncthreads();
    comb(Mi, Ti, M2, T2);
    sm[t] = Mi; st_[t] = Ti;
    __syncthreads();
  }
  float Mx = -INFINITY, Tx = 0.f;
  if (t + 1 < 256) { Mx = sm[t + 1]; Tx = st_[t + 1]; }
  comb(Mx, Tx, sufM[b * nseg + seg], sufT[b * nseg + seg]);
  double lsum = 0.0;
  {
    float s = s1;
    if (Tx == 0.f) { Mx = s; Tx = 1.f; }
    else if (s > Mx) { Tx = Tx * expf(Mx - s) + 1.f; Mx = s; }
    else Tx += expf(s - Mx);
    lsum += (double)Mx + (double)logf(Tx);
    s = s0;
    if (s > Mx) { Tx = Tx * expf(Mx - s) + 1.f; Mx = s; }
    else Tx += expf(s - Mx);
    lsum += (double)Mx + (double)logf(Tx);
  }
  __shared__ double sd[256];
  sd[t] = lsum;
  __syncthreads();
  for (int off = 128; off > 0; off >>= 1) { if (t < off) sd[t] += sd[t + off]; __syncthreads(); }
  if (t == 0) atomicAdd(&acc[row * 8 + b], -sd[0]);
}

// conv1 batched over 4 batches; mm is block-uniform (derived from blockIdx only)
// so weight/bias reads are scalar (s_load via constant cache), not LDS/VALU.
__global__ void k_conv1b(const unsigned* __restrict__ permg, const float* __restrict__ pmw,
                         const float* __restrict__ pmb, float* __restrict__ mf) {
  int t = threadIdx.x;
  int b4 = blockIdx.x / NBLK_MEM;
  int g0 = (blockIdx.x % NBLK_MEM) * 256;     // block-uniform
  int mm = g0 >> 16;                          // uniform: blocks never straddle 65536
  int p = (g0 & 65535) + t;
  int i = p >> 8, j = p & 255;
  const unsigned* ad = permg + (size_t)b4 * NMEM + mm * 65536;
  float nb[3][3];
  #pragma unroll
  for (int di = 0; di < 3; di++)
    #pragma unroll
    for (int dj = 0; dj < 3; dj++) {
      int ii = i + di - 1, jj = j + dj - 1;
      nb[di][dj] = (ii >= 0 && ii < 256 && jj >= 0 && jj < 256) ? (float)ad[ii * 256 + jj] : 0.f;
    }
  unsigned c = ad[p];
  float o[8];
  #pragma unroll
  for (int oc = 0; oc < 8; oc++) {
    float s = pmb[mm * 8 + oc];
    #pragma unroll
    for (int di = 0; di < 3; di++)
      #pragma unroll
      for (int dj = 0; dj < 3; dj++)
        s += pmw[mm * 72 + oc * 9 + di * 3 + dj] * nb[di][dj];
    o[oc] = fmaxf(s, 0.f);
  }
  float4* dst = (float4*)(mf + ((size_t)b4 * NMEM + c) * 8);
  dst[0] = make_float4(o[0], o[1], o[2], o[3]);
  dst[1] = make_float4(o[4], o[5], o[6], o[7]);
}

// conv2 (R3 structure, global nb loads = cache hits), weights/bias read directly
// from global with compile-time-constant indices -> scalar loads.
__global__ void k_conv2b(const float* __restrict__ mf, const float* __restrict__ mcw,
                         const float* __restrict__ mcb, double* __restrict__ part, int gb) {
  __shared__ float pw[4][16][4];
  int t = threadIdx.x;
  int b4 = blockIdx.x / NBLK_MEM;
  int blk = blockIdx.x % NBLK_MEM;
  int r = blk * 32 + (t >> 3);
  int l = t & 7;
  const float* base = mf + (size_t)b4 * (NMEM * 8);
  float nb[9][8];
  #pragma unroll
  for (int q = 0; q < 9; q++) {
    int rr = r + q / 3 - 1, ll = l + q % 3 - 1;
    if (rr >= 0 && rr < 24576 && ll >= 0 && ll < 8) {
      const float4* px = (const float4*)(base + ((size_t)rr * 8 + ll) * 8);
      float4 a = px[0], bb = px[1];
      nb[q][0] = a.x; nb[q][1] = a.y; nb[q][2] = a.z; nb[q][3] = a.w;
      nb[q][4] = bb.x; nb[q][5] = bb.y; nb[q][6] = bb.z; nb[q][7] = bb.w;
    } else {
      #pragma unroll
      for (int c = 0; c < 8; c++) nb[q][c] = 0.f;
    }
  }
  int lane = t & 63, wv = t >> 6;
  #pragma unroll
  for (int c2 = 0; c2 < 16; c2++) {
    float s = mcb[c2];
    #pragma unroll
    for (int c = 0; c < 8; c++)
      #pragma unroll
      for (int q = 0; q < 9; q++)
        s += mcw[c2 * 72 + c * 9 + q] * nb[q][c];
    float v = fmaxf(s, 0.f);
    v += __shfl_xor(v, 1);
    v += __shfl_xor(v, 8);
    v += __shfl_xor(v, 16);
    v += __shfl_xor(v, 32);
    if ((lane & 1) == 0 && ((t >> 3) & 7) == 0) pw[wv][c2][(lane & 7) >> 1] = v;
  }
  __syncthreads();
  if (t < 64) {
    int c2 = t >> 2, d = t & 3;
    double s = (double)pw[0][c2][d] + (double)pw[1][c2][d] + (double)pw[2][c2][d] + (double)pw[3][c2][d];
    part[((size_t)(gb + b4) * NBLK_MEM + blk) * 64 + t] = s;
  }
}

__global__ void k_pool_final(const double* __restrict__ part, double* __restrict__ pooled) {
  int b = blockIdx.x, t = threadIdx.x;       // t = c2*16 + a*4 + d
  int c2 = t >> 4, a = (t >> 2) & 3, d = t & 3;
  double s = 0.0;
  for (int j = 0; j < 192; j++)
    s += part[((size_t)b * NBLK_MEM + a * 192 + j) * 64 + c2 * 4 + d];
  pooled[b * 256 + t] = s / 12288.0;
}

__global__ void k_oplogits(const float* __restrict__ pjw, const float* __restrict__ pjb,
                           const double* __restrict__ pooled, const float* __restrict__ gop,
                           float* __restrict__ oplog, unsigned long long* __restrict__ opkv) {
  __shared__ double pl[8][256];
  int t = threadIdx.x;
  #pragma unroll
  for (int b = 0; b < 8; b++) pl[b][t] = pooled[b * 256 + t];
  __syncthreads();
  int k = blockIdx.x * 256 + t;
  const float4* row = (const float4*)(pjw + (size_t)k * 256);
  double acc[8];
  #pragma unroll
  for (int b = 0; b < 8; b++) acc[b] = 0.0;
  for (int j4 = 0; j4 < 64; j4++) {
    float4 w = row[j4];
    int j = j4 * 4;
    #pragma unroll
    for (int b = 0; b < 8; b++)
      acc[b] += (double)w.x * pl[b][j] + (double)w.y * pl[b][j + 1]
              + (double)w.z * pl[b][j + 2] + (double)w.w * pl[b][j + 3];
  }
  float bias = pjb[k];
  #pragma unroll
  for (int b = 0; b < 8; b++) {
    float ol = (float)(acc[b] + (double)bias);
    oplog[(size_t)b * NOP + k] = ol;
    float key = ol + gop[(size_t)b * NOP + k];
    opkv[(size_t)b * NOP + k] = ((unsigned long long)keymap(key) << 32) | (unsigned)k;
  }
}

static __device__ __forceinline__ float tierf(float h) {
  return h <= 2.f ? 1.f : (h <= 4.f ? 1.5f : (h <= 8.f ? 2.f : (h <= 16.f ? 3.f : 5.f)));
}
static __device__ __forceinline__ double penf(float d) {
  float fwd = d > 0.f ? d : 0.f;
  float bwd = d < 0.f ? -d : 0.f;
  return (double)(fwd * tierf(fwd)) + (double)(bwd * bwd * tierf(bwd));
}

// fused intra (row 1) + inter (row 0) penalties; batch->XCD pinned
__global__ void k_pen(const unsigned* __restrict__ perm, const unsigned* __restrict__ oo,
                      double* __restrict__ acc) {
  int b = blockIdx.x % NB;
  int k = (blockIdx.x / NB) * 256 + threadIdx.x;
  const unsigned* P = perm + (size_t)b * NMEM;
  float A = (float)P[k], Bv = (float)P[NOP + k], Cv = (float)P[2 * NOP + k];
  double pi = penf(Bv - A) + penf(Cv - Bv);
  double pe = 0.0;
  if (k < 65535) {
    unsigned k0 = oo[(size_t)b * NOP + k], k1 = oo[(size_t)b * NOP + k + 1];
    pe = penf((float)P[k1] - (float)P[2 * NOP + k0]);
  }
  __shared__ double ri[256], re[256];
  ri[threadIdx.x] = pi; re[threadIdx.x] = pe;
  __syncthreads();
  for (int off = 128; off > 0; off >>= 1) {
    if (threadIdx.x < off) { ri[threadIdx.x] += ri[threadIdx.x + off]; re[threadIdx.x] += re[threadIdx.x + off]; }
    __syncthreads();
  }
  if (threadIdx.x == 0) { atomicAdd(&acc[8 + b], ri[0]); atomicAdd(&acc[0 + b], re[0]); }
}

__global__ void k_finalize(const double* __restrict__ acc, float* __restrict__ out) {
  if (threadIdx.x < 32) out[threadIdx.x] = (float)acc[threadIdx.x];
}

extern "C" void kernel_launch(void* const* d_in, const int* in_sizes, int n_in,
                              void* d_out, int out_size, void* d_ws, size_t ws_size,
                              hipStream_t stream) {
  (void)in_sizes; (void)n_in; (void)out_size; (void)ws_size;
  const float* ml  = (const float*)d_in[0];
  const float* gm  = (const float*)d_in[1];
  const float* gop = (const float*)d_in[2];
  const float* pmw = (const float*)d_in[3];
  const float* pmb = (const float*)d_in[4];
  const float* mcw = (const float*)d_in[5];
  const float* mcb = (const float*)d_in[6];
  const float* pjw = (const float*)d_in[7];
  const float* pjb = (const float*)d_in[8];
  float* out = (float*)d_out;
  char* ws = (char*)d_ws;

  unsigned long long* kvA = (unsigned long long*)(ws + 0);          // 12,582,912
  unsigned long long* kvB = (unsigned long long*)(ws + 12582912);   // 12,582,912
  unsigned* hist   = (unsigned*)(ws + 25165824);                    //  <= 393,216
  unsigned* perm   = (unsigned*)(ws + 31457280);                    //  6,291,456
  double*   part   = (double*)(ws + 37748736);                      //  3,145,728
  double*   pooled = (double*)(ws + 40894464);
  double*   acc    = (double*)(ws + 40910848);
  float*    segM   = (float*)(ws + 40911104);
  float*    segT   = (float*)(ws + 40923392);
  float*    sufM   = (float*)(ws + 40935680);
  float*    sufT   = (float*)(ws + 40947968);
  float*    slog  = (float*)(ws + 12582912);                        // reuses dead kvB
  float* mf = (float*)(ws + 0);                                     // conv phase reuse (25.1 MB)
  unsigned long long* opkvA = (unsigned long long*)(ws + 0);
  unsigned long long* opkvB = (unsigned long long*)(ws + 4194304);
  float*    oplog = (float*)(ws + 8388608);
  unsigned* oo    = (unsigned*)(ws + 10485760);

  k_zero<<<1, 32, 0, stream>>>(acc);

  // ---- mem argsort: pass0 builds keys on the fly; pass3 writes perm directly ----
  k_radix_hist0<<<NB * NC_MEM, 256, 0, stream>>>(ml, gm, hist);
  k_radix_scan<<<NB, 1024, 0, stream>>>(hist, 256 * NC_MEM);
  k_radix_scatter0<<<NB * NC_MEM, 256, 0, stream>>>(ml, gm, kvA, hist);
  k_radix_hist<<<NB * NC_MEM, 256, 0, stream>>>(kvA, hist, NMEM, NC_MEM, 40);
  k_radix_scan<<<NB, 1024, 0, stream>>>(hist, 256 * NC_MEM);
  k_radix_scatter<<<NB * NC_MEM, 256, 0, stream>>>(kvA, kvB, hist, NMEM, NC_MEM, 40);
  k_radix_hist<<<NB * NC_MEM, 256, 0, stream>>>(kvB, hist, NMEM, NC_MEM, 48);
  k_radix_scan<<<NB, 1024, 0, stream>>>(hist, 256 * NC_MEM);
  k_radix_scatter<<<NB * NC_MEM, 256, 0, stream>>>(kvB, kvA, hist, NMEM, NC_MEM, 48);
  k_radix_hist<<<NB * NC_MEM, 256, 0, stream>>>(kvA, hist, NMEM, NC_MEM, 56);
  k_radix_scan<<<NB, 1024, 0, stream>>>(hist, 256 * NC_MEM);
  k_radix_scatter_lo<<<NB * NC_MEM, 256, 0, stream>>>(kvA, perm, hist, NMEM, NC_MEM);

  // mem PL logprob (row 3)
  {
    int nseg = NMEM / LSEG;  // 384
    kpl_seg <<<NB * (nseg / 4), 256, 0, stream>>>(ml, perm, NMEM, nseg, segM, segT, slog, acc, 3);
    kpl_scan<<<NB, 512, 0, stream>>>(segM, segT, nseg, sufM, sufT);
    kpl_main<<<NB * nseg, 256, 0, stream>>>(slog, NMEM, nseg, sufM, sufT, acc, 3);
  }

  // ---- conv1 + conv2 + pooling, 2 groups of 4 batches ----
  for (int g = 0; g < 2; g++) {
    k_conv1b<<<4 * NBLK_MEM, 256, 0, stream>>>(perm + (size_t)g * 4 * NMEM, pmw, pmb, mf);
    k_conv2b<<<4 * NBLK_MEM, 256, 0, stream>>>(mf, mcw, mcb, part, g * 4);
  }
  k_pool_final<<<NB, 256, 0, stream>>>(part, pooled);

  // ---- op logits + keys ----
  k_oplogits<<<NOP / 256, 256, 0, stream>>>(pjw, pjb, pooled, gop, oplog, opkvA);

  // ---- op argsort: pass3 writes oo directly ----
  k_radix_hist<<<NB * NC_OP, 256, 0, stream>>>(opkvA, hist, NOP, NC_OP, 32);
  k_radix_scan<<<NB, 1024, 0, stream>>>(hist, 256 * NC_OP);
  k_radix_scatter<<<NB * NC_OP, 256, 0, stream>>>(opkvA, opkvB, hist, NOP, NC_OP, 32);
  k_radix_hist<<<NB * NC_OP, 256, 0, stream>>>(opkvB, hist, NOP, NC_OP, 40);
  k_radix_scan<<<NB, 1024, 0, stream>>>(hist, 256 * NC_OP);
  k_radix_scatter<<<NB * NC_OP, 256, 0, stream>>>(opkvB, opkvA, hist, NOP, NC_OP, 40);
  k_radix_hist<<<NB * NC_OP, 256, 0, stream>>>(opkvA, hist, NOP, NC_OP, 48);
  k_radix_scan<<<NB, 1024, 0, stream>>>(hist, 256 * NC_OP);
  k_radix_scatter<<<NB * NC_OP, 256, 0, stream>>>(opkvA, opkvB, hist, NOP, NC_OP, 48);
  k_radix_hist<<<NB * NC_OP, 256, 0, stream>>>(opkvB, hist, NOP, NC_OP, 56);
  k_radix_scan<<<NB, 1024, 0, stream>>>(hist, 256 * NC_OP);
  k_radix_scatter_lo<<<NB * NC_OP, 256, 0, stream>>>(opkvB, oo, hist, NOP, NC_OP);

  // op PL logprob (row 2)
  {
    int nseg = NOP / LSEG;   // 128
    kpl_seg <<<NB * (nseg / 4), 256, 0, stream>>>(oplog, oo, NOP, nseg, segM, segT, slog, acc, 2);
    kpl_scan<<<NB, 512, 0, stream>>>(segM, segT, nseg, sufM, sufT);
    kpl_main<<<NB * nseg, 256, 0, stream>>>(slog, NOP, nseg, sufM, sufT, acc, 2);
  }

  // penalties (rows 0,1)
  k_pen<<<NB * NOP / 256, 256, 0, stream>>>(perm, oo, acc);

  k_finalize<<<1, 32, 0, stream>>>(acc, out);
}

// Round 13
// 425.417 us; speedup vs baseline: 9.1972x; 1.0877x over previous
//
#include <hip/hip_runtime.h>
#include <math.h>

#define NB 8
#define NMEM 196608
#define NOP 65536
#define NBLK_MEM 768
#define LSEG 512
#define EPB 4096
#define NC_MEM 48   // NMEM / EPB
#define NC_OP 16    // NOP / EPB

static __device__ __forceinline__ unsigned keymap(float f) {
  unsigned u = __float_as_uint(f);
  return (u & 0x80000000u) ? ~u : (u | 0x80000000u);
}

// logsumexp state combiner: (M,T) represents M + log(T); T==0 is identity.
static __device__ __forceinline__ void comb(float& M1, float& T1, float M2, float T2) {
  if (T2 == 0.f) return;
  if (T1 == 0.f) { M1 = M2; T1 = T2; return; }
  float M = fmaxf(M1, M2);
  T1 = T1 * expf(M1 - M) + T2 * expf(M2 - M);
  M1 = M;
}

__global__ void k_zero(double* acc) {
  if (threadIdx.x < 32) acc[threadIdx.x] = 0.0;
}

// ---- radix sort: 4x8-bit passes, stable, 4096 elements/block ----
// Batch->XCD pinning: batch = blockIdx.x % 8, so all blocks of one batch land
// on one XCD (round-robin dispatch) and its working set stays in that L2.
__global__ void k_radix_hist0(const float* __restrict__ ml, const float* __restrict__ gm,
                              unsigned* __restrict__ hist) {
  __shared__ unsigned h[256];
  int batch = blockIdx.x % NB, cb = blockIdx.x / NB;
  int t = threadIdx.x;
  h[t] = 0;
  __syncthreads();
  const float* pm = ml + (size_t)batch * NMEM + (size_t)cb * EPB;
  const float* pg = gm + (size_t)batch * NMEM + (size_t)cb * EPB;
  #pragma unroll
  for (int r = 0; r < 16; r++) {
    unsigned key = keymap(pm[r * 256 + t] + pg[r * 256 + t]);
    atomicAdd(&h[key & 255u], 1u);
  }
  __syncthreads();
  hist[((size_t)batch * 256 + t) * NC_MEM + cb] = h[t];
}

__global__ void k_radix_hist(const unsigned long long* __restrict__ src, unsigned* __restrict__ hist,
                             int nper, int nblk, int shift) {
  __shared__ unsigned h[256];
  int batch = blockIdx.x % NB, cb = blockIdx.x / NB;
  int t = threadIdx.x;
  h[t] = 0;
  __syncthreads();
  const unsigned long long* p = src + (size_t)batch * nper + (size_t)cb * EPB;
  #pragma unroll
  for (int r = 0; r < 16; r++) {
    unsigned long long v = p[r * 256 + t];
    unsigned d = (unsigned)(v >> shift) & 255u;
    atomicAdd(&h[d], 1u);
  }
  __syncthreads();
  hist[((size_t)batch * 256 + t) * nblk + cb] = h[t];
}

__global__ void __launch_bounds__(1024) k_radix_scan(unsigned* __restrict__ hist, int L) {
  int b = blockIdx.x, t = threadIdx.x;   // block b -> XCD b%8: hist L2-hot
  unsigned* h = hist + (size_t)b * L;
  int C = L / 1024;
  unsigned s = 0;
  for (int i = 0; i < C; i++) s += h[t * C + i];
  __shared__ unsigned ls[1024];
  ls[t] = s;
  __syncthreads();
  for (int off = 1; off < 1024; off <<= 1) {
    unsigned add = (t >= off) ? ls[t - off] : 0u;
    __syncthreads();
    ls[t] += add;
    __syncthreads();
  }
  unsigned run = (t > 0) ? ls[t - 1] : 0u;
  for (int i = 0; i < C; i++) { unsigned v = h[t * C + i]; h[t * C + i] = run; run += v; }
}

// stable in-block rank: pos = base[d] + run[d] + wave-exclusive + ballot lane rank.
#define SCATTER_BODY(GETV, WRITE)                                              \
  __shared__ unsigned base[256];                                               \
  __shared__ unsigned run[256];                                                \
  __shared__ unsigned wh[4][256];                                              \
  int t = threadIdx.x, lane = t & 63, wv = t >> 6;                             \
  base[t] = hist[((size_t)batch * 256 + t) * nblk + cb];                       \
  run[t] = 0;                                                                  \
  unsigned long long v[16];                                                    \
  GETV;                                                                        \
  __syncthreads();                                                             \
  _Pragma("unroll")                                                            \
  for (int r = 0; r < 16; r++) {                                               \
    unsigned d = (unsigned)(v[r] >> shift) & 255u;                             \
    unsigned long long m = ~0ull;                                              \
    _Pragma("unroll")                                                          \
    for (int bit = 0; bit < 8; bit++) {                                        \
      unsigned long long bal = __ballot((d >> bit) & 1u);                      \
      m &= ((d >> bit) & 1u) ? bal : ~bal;                                     \
    }                                                                          \
    unsigned rank = (unsigned)__popcll(m & ((1ull << lane) - 1ull));           \
    _Pragma("unroll")                                                          \
    for (int w = 0; w < 4; w++) wh[w][t] = 0;                                  \
    __syncthreads();                                                           \
    if (rank == 0) wh[wv][d] = (unsigned)__popcll(m);                          \
    __syncthreads();                                                           \
    {                                                                          \
      unsigned run_t = run[t];                                                 \
      _Pragma("unroll")                                                        \
      for (int w = 0; w < 4; w++) { unsigned x = wh[w][t]; wh[w][t] = run_t; run_t += x; } \
      run[t] = run_t;                                                          \
    }                                                                          \
    __syncthreads();                                                           \
    unsigned pos = base[d] + wh[wv][d] + rank;                                 \
    WRITE;                                                                     \
    __syncthreads();                                                           \
  }

__global__ void k_radix_scatter0(const float* __restrict__ ml, const float* __restrict__ gm,
                                 unsigned long long* __restrict__ dst, const unsigned* __restrict__ hist) {
  int batch = blockIdx.x % NB, cb = blockIdx.x / NB;
  const int nblk = NC_MEM, shift = 32;
  const float* pm = ml + (size_t)batch * NMEM + (size_t)cb * EPB;
  const float* pg = gm + (size_t)batch * NMEM + (size_t)cb * EPB;
  unsigned long long* q = dst + (size_t)batch * NMEM;
  SCATTER_BODY(
    { _Pragma("unroll")
      for (int r = 0; r < 16; r++) {
        unsigned key = keymap(pm[r * 256 + t] + pg[r * 256 + t]);
        v[r] = ((unsigned long long)key << 32) | (unsigned)(cb * EPB + r * 256 + t);
      } },
    { q[pos] = v[r]; })
}

__global__ void k_radix_scatter(const unsigned long long* __restrict__ src, unsigned long long* __restrict__ dst,
                                const unsigned* __restrict__ hist, int nper, int nblk, int shift) {
  int batch = blockIdx.x % NB, cb = blockIdx.x / NB;
  const unsigned long long* p = src + (size_t)batch * nper + (size_t)cb * EPB;
  unsigned long long* q = dst + (size_t)batch * nper;
  SCATTER_BODY(
    { _Pragma("unroll")
      for (int r = 0; r < 16; r++) v[r] = p[r * 256 + t]; },
    { q[pos] = v[r]; })
}

// last pass: write only the low 32 bits (the permutation index).
__global__ void k_radix_scatter_lo(const unsigned long long* __restrict__ src, unsigned* __restrict__ dst,
                                   const unsigned* __restrict__ hist, int nper, int nblk) {
  int batch = blockIdx.x % NB, cb = blockIdx.x / NB;
  const int shift = 56;
  const unsigned long long* p = src + (size_t)batch * nper + (size_t)cb * EPB;
  unsigned* q = dst + (size_t)batch * nper;
  SCATTER_BODY(
    { _Pragma("unroll")
      for (int r = 0; r < 16; r++) v[r] = p[r * 256 + t]; },
    { q[pos] = (unsigned)v[r]; })
}

// ---- Plackett-Luce: segmented reverse-cumlogsumexp ----
// Pass 1: one WAVE per segment (4 segments/block); each lane gathers 8 elements
// (high ILP), stores them contiguous to slog; 6-round shuffle butterfly reduce
// (no barriers). One f64 atomic per block.
__global__ void kpl_seg(const float* __restrict__ logits, const unsigned* __restrict__ order,
                        int n, int nseg, float* __restrict__ segM, float* __restrict__ segT,
                        float* __restrict__ slog, double* __restrict__ acc, int row) {
  int b = blockIdx.x % NB;
  int sg = blockIdx.x / NB;
  int t = threadIdx.x, lane = t & 63, wv = t >> 6;
  int seg = sg * 4 + wv;
  const float* lg = logits + (size_t)b * n;
  const unsigned* od = order + (size_t)b * n + (size_t)seg * LSEG + lane * 8;
  uint4 i0 = *((const uint4*)od);
  uint4 i1 = *((const uint4*)(od + 4));
  float s0 = lg[i0.x], s1 = lg[i0.y], s2 = lg[i0.z], s3 = lg[i0.w];
  float s4 = lg[i1.x], s5 = lg[i1.y], s6 = lg[i1.z], s7 = lg[i1.w];
  float* sl = slog + (size_t)b * n + (size_t)seg * LSEG + lane * 8;
  *((float4*)sl) = make_float4(s0, s1, s2, s3);
  *((float4*)(sl + 4)) = make_float4(s4, s5, s6, s7);
  float m = fmaxf(fmaxf(fmaxf(s0, s1), fmaxf(s2, s3)),
                  fmaxf(fmaxf(s4, s5), fmaxf(s6, s7)));
  float T = expf(s0 - m) + expf(s1 - m) + expf(s2 - m) + expf(s3 - m)
          + expf(s4 - m) + expf(s5 - m) + expf(s6 - m) + expf(s7 - m);
  double ss = ((double)s0 + (double)s1) + ((double)s2 + (double)s3)
            + ((double)s4 + (double)s5) + ((double)s6 + (double)s7);
  #pragma unroll
  for (int off = 1; off < 64; off <<= 1) {
    float M2 = __shfl_xor(m, off);
    float T2 = __shfl_xor(T, off);
    comb(m, T, M2, T2);
    ss += __shfl_xor(ss, off);
  }
  __shared__ double sw[4];
  if (lane == 0) { segM[b * nseg + seg] = m; segT[b * nseg + seg] = T; sw[wv] = ss; }
  __syncthreads();
  if (t == 0) atomicAdd(&acc[row * 8 + b], (sw[0] + sw[1]) + (sw[2] + sw[3]));
}

__global__ void __launch_bounds__(512) kpl_scan(const float* __restrict__ segM, const float* __restrict__ segT,
                                                int nseg, float* __restrict__ sufM, float* __restrict__ sufT) {
  int b = blockIdx.x, t = threadIdx.x;
  __shared__ float sm[512], st_[512];
  float M = -INFINITY, T = 0.f;
  if (t < nseg) { M = segM[b * nseg + t]; T = segT[b * nseg + t]; }
  sm[t] = M; st_[t] = T;
  __syncthreads();
  for (int off = 1; off < 512; off <<= 1) {
    float M2 = -INFINITY, T2 = 0.f;
    if (t + off < 512) { M2 = sm[t + off]; T2 = st_[t + off]; }
    __syncthreads();
    comb(M, T, M2, T2);
    sm[t] = M; st_[t] = T;
    __syncthreads();
  }
  if (t < nseg) {
    float eM = -INFINITY, eT = 0.f;
    if (t + 1 < nseg) { eM = sm[t + 1]; eT = st_[t + 1]; }
    sufM[b * nseg + t] = eM; sufT[b * nseg + t] = eT;
  }
}

// Pass 3: one WAVE per segment; lane owns 8 consecutive slog elements.
// 6-round shfl_down suffix scan (no barriers), then 8-step in-register state
// walk with the logf's hoisted out of the dependent chain.
__global__ void kpl_main(const float* __restrict__ slog, int n, int nseg,
                         const float* __restrict__ sufM, const float* __restrict__ sufT,
                         double* __restrict__ acc, int row) {
  int b = blockIdx.x % NB;
  int sg = blockIdx.x / NB;
  int t = threadIdx.x, lane = t & 63, wv = t >> 6;
  int seg = sg * 4 + wv;
  const float* sl = slog + (size_t)b * n + (size_t)seg * LSEG + lane * 8;
  float4 a = *((const float4*)sl);
  float4 c = *((const float4*)(sl + 4));
  float s[8] = {a.x, a.y, a.z, a.w, c.x, c.y, c.z, c.w};
  // lane-local combined state (all 8 elements)
  float m = fmaxf(fmaxf(fmaxf(s[0], s[1]), fmaxf(s[2], s[3])),
                  fmaxf(fmaxf(s[4], s[5]), fmaxf(s[6], s[7])));
  float T = expf(s[0] - m) + expf(s[1] - m) + expf(s[2] - m) + expf(s[3] - m)
          + expf(s[4] - m) + expf(s[5] - m) + expf(s[6] - m) + expf(s[7] - m);
  // inclusive suffix scan over lanes (comb is symmetric -> direction-safe)
  #pragma unroll
  for (int off = 1; off < 64; off <<= 1) {
    float M2 = __shfl_down(m, off);
    float T2 = __shfl_down(T, off);
    if (lane + off < 64) comb(m, T, M2, T2);
  }
  // exclusive: take inclusive of lane+1; lane 63 gets identity
  float Mx = __shfl_down(m, 1);
  float Tx = __shfl_down(T, 1);
  if (lane == 63) { Mx = -INFINITY; Tx = 0.f; }
  // fold in the segment-exclusive suffix
  comb(Mx, Tx, sufM[b * nseg + seg], sufT[b * nseg + seg]);
  // serial state walk back-to-front, recording per-position states
  float Ms[8], Ts[8];
  #pragma unroll
  for (int i = 7; i >= 0; i--) {
    float sv = s[i];
    if (Tx == 0.f) { Mx = sv; Tx = 1.f; }
    else if (sv > Mx) { Tx = Tx * expf(Mx - sv) + 1.f; Mx = sv; }
    else Tx += expf(sv - Mx);
    Ms[i] = Mx; Ts[i] = Tx;
  }
  // 8 independent logs (off the dependent chain)
  double lsum = 0.0;
  #pragma unroll
  for (int i = 0; i < 8; i++) lsum += (double)Ms[i] + (double)logf(Ts[i]);
  #pragma unroll
  for (int off = 1; off < 64; off <<= 1) lsum += __shfl_xor(lsum, off);
  __shared__ double sw[4];
  if (lane == 0) sw[wv] = lsum;
  __syncthreads();
  if (t == 0) atomicAdd(&acc[row * 8 + b], -((sw[0] + sw[1]) + (sw[2] + sw[3])));
}

// conv1 batched over 4 batches; mm is block-uniform (derived from blockIdx only)
// so weight/bias reads are scalar (s_load via constant cache), not LDS/VALU.
__global__ void k_conv1b(const unsigned* __restrict__ permg, const float* __restrict__ pmw,
                         const float* __restrict__ pmb, float* __restrict__ mf) {
  int t = threadIdx.x;
  int b4 = blockIdx.x / NBLK_MEM;
  int g0 = (blockIdx.x % NBLK_MEM) * 256;     // block-uniform
  int mm = g0 >> 16;                          // uniform: blocks never straddle 65536
  int p = (g0 & 65535) + t;
  int i = p >> 8, j = p & 255;
  const unsigned* ad = permg + (size_t)b4 * NMEM + mm * 65536;
  float nb[3][3];
  #pragma unroll
  for (int di = 0; di < 3; di++)
    #pragma unroll
    for (int dj = 0; dj < 3; dj++) {
      int ii = i + di - 1, jj = j + dj - 1;
      nb[di][dj] = (ii >= 0 && ii < 256 && jj >= 0 && jj < 256) ? (float)ad[ii * 256 + jj] : 0.f;
    }
  unsigned c = ad[p];
  float o[8];
  #pragma unroll
  for (int oc = 0; oc < 8; oc++) {
    float s = pmb[mm * 8 + oc];
    #pragma unroll
    for (int di = 0; di < 3; di++)
      #pragma unroll
      for (int dj = 0; dj < 3; dj++)
        s += pmw[mm * 72 + oc * 9 + di * 3 + dj] * nb[di][dj];
    o[oc] = fmaxf(s, 0.f);
  }
  float4* dst = (float4*)(mf + ((size_t)b4 * NMEM + c) * 8);
  dst[0] = make_float4(o[0], o[1], o[2], o[3]);
  dst[1] = make_float4(o[4], o[5], o[6], o[7]);
}

// conv2 (R3 structure, global nb loads = cache hits), weights/bias read directly
// from global with compile-time-constant indices -> scalar loads.
__global__ void k_conv2b(const float* __restrict__ mf, const float* __restrict__ mcw,
                         const float* __restrict__ mcb, double* __restrict__ part, int gb) {
  __shared__ float pw[4][16][4];
  int t = threadIdx.x;
  int b4 = blockIdx.x / NBLK_MEM;
  int blk = blockIdx.x % NBLK_MEM;
  int r = blk * 32 + (t >> 3);
  int l = t & 7;
  const float* base = mf + (size_t)b4 * (NMEM * 8);
  float nb[9][8];
  #pragma unroll
  for (int q = 0; q < 9; q++) {
    int rr = r + q / 3 - 1, ll = l + q % 3 - 1;
    if (rr >= 0 && rr < 24576 && ll >= 0 && ll < 8) {
      const float4* px = (const float4*)(base + ((size_t)rr * 8 + ll) * 8);
      float4 a = px[0], bb = px[1];
      nb[q][0] = a.x; nb[q][1] = a.y; nb[q][2] = a.z; nb[q][3] = a.w;
      nb[q][4] = bb.x; nb[q][5] = bb.y; nb[q][6] = bb.z; nb[q][7] = bb.w;
    } else {
      #pragma unroll
      for (int c = 0; c < 8; c++) nb[q][c] = 0.f;
    }
  }
  int lane = t & 63, wv = t >> 6;
  #pragma unroll
  for (int c2 = 0; c2 < 16; c2++) {
    float s = mcb[c2];
    #pragma unroll
    for (int c = 0; c < 8; c++)
      #pragma unroll
      for (int q = 0; q < 9; q++)
        s += mcw[c2 * 72 + c * 9 + q] * nb[q][c];
    float v = fmaxf(s, 0.f);
    v += __shfl_xor(v, 1);
    v += __shfl_xor(v, 8);
    v += __shfl_xor(v, 16);
    v += __shfl_xor(v, 32);
    if ((lane & 1) == 0 && ((t >> 3) & 7) == 0) pw[wv][c2][(lane & 7) >> 1] = v;
  }
  __syncthreads();
  if (t < 64) {
    int c2 = t >> 2, d = t & 3;
    double s = (double)pw[0][c2][d] + (double)pw[1][c2][d] + (double)pw[2][c2][d] + (double)pw[3][c2][d];
    part[((size_t)(gb + b4) * NBLK_MEM + blk) * 64 + t] = s;
  }
}

__global__ void k_pool_final(const double* __restrict__ part, double* __restrict__ pooled) {
  int b = blockIdx.x, t = threadIdx.x;       // t = c2*16 + a*4 + d
  int c2 = t >> 4, a = (t >> 2) & 3, d = t & 3;
  double s = 0.0;
  for (int j = 0; j < 192; j++)
    s += part[((size_t)b * NBLK_MEM + a * 192 + j) * 64 + c2 * 4 + d];
  pooled[b * 256 + t] = s / 12288.0;
}

__global__ void k_oplogits(const float* __restrict__ pjw, const float* __restrict__ pjb,
                           const double* __restrict__ pooled, const float* __restrict__ gop,
                           float* __restrict__ oplog, unsigned long long* __restrict__ opkv) {
  __shared__ double pl[8][256];
  int t = threadIdx.x;
  #pragma unroll
  for (int b = 0; b < 8; b++) pl[b][t] = pooled[b * 256 + t];
  __syncthreads();
  int k = blockIdx.x * 256 + t;
  const float4* row = (const float4*)(pjw + (size_t)k * 256);
  double acc[8];
  #pragma unroll
  for (int b = 0; b < 8; b++) acc[b] = 0.0;
  for (int j4 = 0; j4 < 64; j4++) {
    float4 w = row[j4];
    int j = j4 * 4;
    #pragma unroll
    for (int b = 0; b < 8; b++)
      acc[b] += (double)w.x * pl[b][j] + (double)w.y * pl[b][j + 1]
              + (double)w.z * pl[b][j + 2] + (double)w.w * pl[b][j + 3];
  }
  float bias = pjb[k];
  #pragma unroll
  for (int b = 0; b < 8; b++) {
    float ol = (float)(acc[b] + (double)bias);
    oplog[(size_t)b * NOP + k] = ol;
    float key = ol + gop[(size_t)b * NOP + k];
    opkv[(size_t)b * NOP + k] = ((unsigned long long)keymap(key) << 32) | (unsigned)k;
  }
}

static __device__ __forceinline__ float tierf(float h) {
  return h <= 2.f ? 1.f : (h <= 4.f ? 1.5f : (h <= 8.f ? 2.f : (h <= 16.f ? 3.f : 5.f)));
}
static __device__ __forceinline__ double penf(float d) {
  float fwd = d > 0.f ? d : 0.f;
  float bwd = d < 0.f ? -d : 0.f;
  return (double)(fwd * tierf(fwd)) + (double)(bwd * bwd * tierf(bwd));
}

// fused intra (row 1) + inter (row 0) penalties; batch->XCD pinned
__global__ void k_pen(const unsigned* __restrict__ perm, const unsigned* __restrict__ oo,
                      double* __restrict__ acc) {
  int b = blockIdx.x % NB;
  int k = (blockIdx.x / NB) * 256 + threadIdx.x;
  const unsigned* P = perm + (size_t)b * NMEM;
  float A = (float)P[k], Bv = (float)P[NOP + k], Cv = (float)P[2 * NOP + k];
  double pi = penf(Bv - A) + penf(Cv - Bv);
  double pe = 0.0;
  if (k < 65535) {
    unsigned k0 = oo[(size_t)b * NOP + k], k1 = oo[(size_t)b * NOP + k + 1];
    pe = penf((float)P[k1] - (float)P[2 * NOP + k0]);
  }
  __shared__ double ri[256], re[256];
  ri[threadIdx.x] = pi; re[threadIdx.x] = pe;
  __syncthreads();
  for (int off = 128; off > 0; off >>= 1) {
    if (threadIdx.x < off) { ri[threadIdx.x] += ri[threadIdx.x + off]; re[threadIdx.x] += re[threadIdx.x + off]; }
    __syncthreads();
  }
  if (threadIdx.x == 0) { atomicAdd(&acc[8 + b], ri[0]); atomicAdd(&acc[0 + b], re[0]); }
}

__global__ void k_finalize(const double* __restrict__ acc, float* __restrict__ out) {
  if (threadIdx.x < 32) out[threadIdx.x] = (float)acc[threadIdx.x];
}

extern "C" void kernel_launch(void* const* d_in, const int* in_sizes, int n_in,
                              void* d_out, int out_size, void* d_ws, size_t ws_size,
                              hipStream_t stream) {
  (void)in_sizes; (void)n_in; (void)out_size; (void)ws_size;
  const float* ml  = (const float*)d_in[0];
  const float* gm  = (const float*)d_in[1];
  const float* gop = (const float*)d_in[2];
  const float* pmw = (const float*)d_in[3];
  const float* pmb = (const float*)d_in[4];
  const float* mcw = (const float*)d_in[5];
  const float* mcb = (const float*)d_in[6];
  const float* pjw = (const float*)d_in[7];
  const float* pjb = (const float*)d_in[8];
  float* out = (float*)d_out;
  char* ws = (char*)d_ws;

  unsigned long long* kvA = (unsigned long long*)(ws + 0);          // 12,582,912
  unsigned long long* kvB = (unsigned long long*)(ws + 12582912);   // 12,582,912
  unsigned* hist   = (unsigned*)(ws + 25165824);                    //  <= 393,216
  unsigned* perm   = (unsigned*)(ws + 31457280);                    //  6,291,456
  double*   part   = (double*)(ws + 37748736);                      //  3,145,728
  double*   pooled = (double*)(ws + 40894464);
  double*   acc    = (double*)(ws + 40910848);
  float*    segM   = (float*)(ws + 40911104);
  float*    segT   = (float*)(ws + 40923392);
  float*    sufM   = (float*)(ws + 40935680);
  float*    sufT   = (float*)(ws + 40947968);
  float*    slog  = (float*)(ws + 12582912);                        // reuses dead kvB
  float* mf = (float*)(ws + 0);                                     // conv phase reuse (25.1 MB)
  unsigned long long* opkvA = (unsigned long long*)(ws + 0);
  unsigned long long* opkvB = (unsigned long long*)(ws + 4194304);
  float*    oplog = (float*)(ws + 8388608);
  unsigned* oo    = (unsigned*)(ws + 10485760);

  k_zero<<<1, 32, 0, stream>>>(acc);

  // ---- mem argsort: pass0 builds keys on the fly; pass3 writes perm directly ----
  k_radix_hist0<<<NB * NC_MEM, 256, 0, stream>>>(ml, gm, hist);
  k_radix_scan<<<NB, 1024, 0, stream>>>(hist, 256 * NC_MEM);
  k_radix_scatter0<<<NB * NC_MEM, 256, 0, stream>>>(ml, gm, kvA, hist);
  k_radix_hist<<<NB * NC_MEM, 256, 0, stream>>>(kvA, hist, NMEM, NC_MEM, 40);
  k_radix_scan<<<NB, 1024, 0, stream>>>(hist, 256 * NC_MEM);
  k_radix_scatter<<<NB * NC_MEM, 256, 0, stream>>>(kvA, kvB, hist, NMEM, NC_MEM, 40);
  k_radix_hist<<<NB * NC_MEM, 256, 0, stream>>>(kvB, hist, NMEM, NC_MEM, 48);
  k_radix_scan<<<NB, 1024, 0, stream>>>(hist, 256 * NC_MEM);
  k_radix_scatter<<<NB * NC_MEM, 256, 0, stream>>>(kvB, kvA, hist, NMEM, NC_MEM, 48);
  k_radix_hist<<<NB * NC_MEM, 256, 0, stream>>>(kvA, hist, NMEM, NC_MEM, 56);
  k_radix_scan<<<NB, 1024, 0, stream>>>(hist, 256 * NC_MEM);
  k_radix_scatter_lo<<<NB * NC_MEM, 256, 0, stream>>>(kvA, perm, hist, NMEM, NC_MEM);

  // mem PL logprob (row 3)
  {
    int nseg = NMEM / LSEG;  // 384
    kpl_seg <<<NB * (nseg / 4), 256, 0, stream>>>(ml, perm, NMEM, nseg, segM, segT, slog, acc, 3);
    kpl_scan<<<NB, 512, 0, stream>>>(segM, segT, nseg, sufM, sufT);
    kpl_main<<<NB * (nseg / 4), 256, 0, stream>>>(slog, NMEM, nseg, sufM, sufT, acc, 3);
  }

  // ---- conv1 + conv2 + pooling, 2 groups of 4 batches ----
  for (int g = 0; g < 2; g++) {
    k_conv1b<<<4 * NBLK_MEM, 256, 0, stream>>>(perm + (size_t)g * 4 * NMEM, pmw, pmb, mf);
    k_conv2b<<<4 * NBLK_MEM, 256, 0, stream>>>(mf, mcw, mcb, part, g * 4);
  }
  k_pool_final<<<NB, 256, 0, stream>>>(part, pooled);

  // ---- op logits + keys ----
  k_oplogits<<<NOP / 256, 256, 0, stream>>>(pjw, pjb, pooled, gop, oplog, opkvA);

  // ---- op argsort: pass3 writes oo directly ----
  k_radix_hist<<<NB * NC_OP, 256, 0, stream>>>(opkvA, hist, NOP, NC_OP, 32);
  k_radix_scan<<<NB, 1024, 0, stream>>>(hist, 256 * NC_OP);
  k_radix_scatter<<<NB * NC_OP, 256, 0, stream>>>(opkvA, opkvB, hist, NOP, NC_OP, 32);
  k_radix_hist<<<NB * NC_OP, 256, 0, stream>>>(opkvB, hist, NOP, NC_OP, 40);
  k_radix_scan<<<NB, 1024, 0, stream>>>(hist, 256 * NC_OP);
  k_radix_scatter<<<NB * NC_OP, 256, 0, stream>>>(opkvB, opkvA, hist, NOP, NC_OP, 40);
  k_radix_hist<<<NB * NC_OP, 256, 0, stream>>>(opkvA, hist, NOP, NC_OP, 48);
  k_radix_scan<<<NB, 1024, 0, stream>>>(hist, 256 * NC_OP);
  k_radix_scatter<<<NB * NC_OP, 256, 0, stream>>>(opkvA, opkvB, hist, NOP, NC_OP, 48);
  k_radix_hist<<<NB * NC_OP, 256, 0, stream>>>(opkvB, hist, NOP, NC_OP, 56);
  k_radix_scan<<<NB, 1024, 0, stream>>>(hist, 256 * NC_OP);
  k_radix_scatter_lo<<<NB * NC_OP, 256, 0, stream>>>(opkvB, oo, hist, NOP, NC_OP);

  // op PL logprob (row 2)
  {
    int nseg = NOP / LSEG;   // 128
    kpl_seg <<<NB * (nseg / 4), 256, 0, stream>>>(oplog, oo, NOP, nseg, segM, segT, slog, acc, 2);
    kpl_scan<<<NB, 512, 0, stream>>>(segM, segT, nseg, sufM, sufT);
    kpl_main<<<NB * (nseg / 4), 256, 0, stream>>>(slog, NOP, nseg, sufM, sufT, acc, 2);
  }

  // penalties (rows 0,1)
  k_pen<<<NB * NOP / 256, 256, 0, stream>>>(perm, oo, acc);

  k_finalize<<<1, 32, 0, stream>>>(acc, out);
}